// Round 3
// baseline (1277.994 us; speedup 1.0000x reference)
//
#include <hip/hip_runtime.h>

typedef unsigned long long u64;
typedef unsigned int u32;
typedef __bf16 bf16;
typedef bf16 bf16x8 __attribute__((ext_vector_type(8)));
typedef float f32x4 __attribute__((ext_vector_type(4)));

#define B_   8
#define C_   256
#define T_   2048
#define NQ   8
#define BINS 1024
#define NROWS (B_ * T_)          // 16384
#define NCODE (NQ * BINS)        // 8192
#define K3   768                 // 3 * C_  (x: hi,hi,lo | cb: hi,lo,hi)

// ---- workspace layout (bytes) ----
#define XS_OFF   ((size_t)0)                       // bf16 [16384][768]  = 25165824
#define CS_OFF   ((size_t)25165824)                // bf16 [8192][768]   = 12582912
#define XT_OFF   ((size_t)37748736)                // f32  [16384][256]  = 16777216
#define CAND_OFF ((size_t)54525952)                // u64  [64][16384][2]= 16777216
#define C2D_OFF  ((size_t)71303168)                // f64  [8192]        = 65536
#define C2F_OFF  ((size_t)71368704)                // f32  [8192]        = 32768
#define IDXI_OFF ((size_t)71401472)                // i32  [131072]      = 524288

static __device__ __forceinline__ void gll16(const void* g, void* l) {
    __builtin_amdgcn_global_load_lds(
        (const __attribute__((address_space(1))) u32*)g,
        (__attribute__((address_space(3))) u32*)l, 16, 0, 0);
}

static __device__ __forceinline__ u32 mapf(float f) {
    u32 u = __float_as_uint(f);
    return (u & 0x80000000u) ? ~u : (u | 0x80000000u);
}

// ---------------- prep_x: transpose + bf16 split -------------------------
// grid 1024 = 8 b * 4 ctile * 32 ttile
__global__ __launch_bounds__(256)
void prep_x(const float* __restrict__ x, float* __restrict__ x_t,
            bf16* __restrict__ xs) {
    __shared__ float tile[64][65];
    const int tid = threadIdx.x;
    const int bid = blockIdx.x;
    const int b  = bid >> 7;
    const int c0 = ((bid >> 5) & 3) * 64;
    const int t0 = (bid & 31) * 64;
    {
        const int j = tid & 63, cg = tid >> 6;
        #pragma unroll
        for (int ii = 0; ii < 16; ++ii) {
            const int cl = cg * 16 + ii;
            tile[cl][j] = x[((size_t)(b * C_ + c0 + cl) * T_) + t0 + j];
        }
    }
    __syncthreads();
    {
        const int cl = tid & 63, tg = tid >> 6;
        #pragma unroll
        for (int jj = 0; jj < 16; ++jj) {
            const int tl = tg * 16 + jj;
            const float v = tile[cl][tl];
            const size_t n = (size_t)b * T_ + t0 + tl;
            x_t[n * C_ + c0 + cl] = v;
            const bf16 hi = (bf16)v;
            const bf16 lo = (bf16)(v - (float)hi);
            xs[n * K3 + c0 + cl]           = hi;   // block 0: hi
            xs[n * K3 + 256 + c0 + cl]     = hi;   // block 1: hi
            xs[n * K3 + 512 + c0 + cl]     = lo;   // block 2: lo
        }
    }
}

// ---------------- prep_cb: bf16 split of codebook ------------------------
// grid 2048, wave per code.  Layout MUST be [hi, lo, hi] so that
// sum_k A'[k]B'[k] = xh*ch + xh*cl + xl*ch   (round-2 bug: was [hi,hi,lo])
struct alignas(8) BPack { bf16 v[4]; };
__global__ __launch_bounds__(256)
void prep_cb(const float* __restrict__ cb, bf16* __restrict__ cs) {
    const int lane = threadIdx.x & 63;
    const int w    = threadIdx.x >> 6;
    const int code = blockIdx.x * 4 + w;
    const float4 v = *(const float4*)(cb + (size_t)code * C_ + lane * 4);
    BPack hp, lp;
    float f[4] = {v.x, v.y, v.z, v.w};
    #pragma unroll
    for (int i = 0; i < 4; ++i) {
        hp.v[i] = (bf16)f[i];
        lp.v[i] = (bf16)(f[i] - (float)hp.v[i]);
    }
    bf16* base = cs + (size_t)code * K3 + lane * 4;
    *(BPack*)(base)       = hp;   // block 0: hi
    *(BPack*)(base + 256) = lp;   // block 1: lo   <-- the fix
    *(BPack*)(base + 512) = hp;   // block 2: hi   <-- the fix
}

// ---------------- c2: per-code squared norm (fp64 + fp32) ----------------
__global__ __launch_bounds__(256)
void c2_kernel(const float* __restrict__ cb, double* __restrict__ c2d,
               float* __restrict__ c2f) {
    const int w    = threadIdx.x >> 6;
    const int lane = threadIdx.x & 63;
    const int code = blockIdx.x * 4 + w;
    const float* row = cb + (size_t)code * C_;
    double s = 0.0;
    #pragma unroll
    for (int i = 0; i < C_ / 64; ++i) {
        const double v = (double)row[lane + i * 64];
        s += v * v;
    }
    #pragma unroll
    for (int off = 32; off; off >>= 1) s += __shfl_down(s, off, 64);
    if (lane == 0) { c2d[code] = s; c2f[code] = (float)s; }
}

// ---------------- dist: bf16 MFMA GEMM + per-block top2 ------------------
// grid = 64 coltiles * 128 rowtiles = 8192 blocks, 256 threads (4 waves 2x2)
__global__ __launch_bounds__(256)
void dist_kernel(const bf16* __restrict__ xs, const bf16* __restrict__ cs,
                 const float* __restrict__ c2f, u64* __restrict__ cand) {
    union SM {
        struct { bf16 A[128 * 32]; bf16 B[128 * 32]; } t;   // 16 KB
        u64 red[128][17];                                   // 17.4 KB
    };
    __shared__ SM sm;

    const int tid  = threadIdx.x;
    const int lane = tid & 63;
    const int w    = tid >> 6;
    const int wr   = w >> 1, wc = w & 1;
    const int bid  = blockIdx.x;
    const int rt   = bid & 127;        // row tile
    const int ct   = bid >> 7;         // col tile (128 consecutive bids share ct)
    const int n0   = rt * 128;
    const int code0 = ct * 128;

    f32x4 acc[4][4];
    #pragma unroll
    for (int m = 0; m < 4; ++m)
        #pragma unroll
        for (int n = 0; n < 4; ++n) {
            f32x4 z = {0.f, 0.f, 0.f, 0.f};
            acc[m][n] = z;
        }

    // staging: wave w stages rows [w*32, w*32+32) in 2 issues of 16 rows
    const int srow   = w * 32 + (lane >> 2);
    const int schunk = (lane & 3) * 8;                       // bf16 elems (16B)
    const bf16* gA = xs + (size_t)(n0 + srow) * K3 + schunk;
    const bf16* gB = cs + (size_t)(code0 + srow) * K3 + schunk;
    bf16* lA0 = &sm.t.A[(w * 32) * 32];
    bf16* lA1 = &sm.t.A[(w * 32 + 16) * 32];
    bf16* lB0 = &sm.t.B[(w * 32) * 32];
    bf16* lB1 = &sm.t.B[(w * 32 + 16) * 32];

    const int rbase = wr * 64 + (lane & 15);
    const int cbase = wc * 64 + (lane & 15);
    const int koff  = (lane >> 4) * 8;

    for (int kt = 0; kt < K3 / 32; ++kt) {
        const int k0 = kt * 32;
        __syncthreads();
        gll16(gA + k0, lA0);
        gll16(gA + k0 + (size_t)16 * K3, lA1);
        gll16(gB + k0, lB0);
        gll16(gB + k0 + (size_t)16 * K3, lB1);
        __syncthreads();

        bf16x8 af[4], bg[4];
        #pragma unroll
        for (int m = 0; m < 4; ++m)
            af[m] = *(const bf16x8*)&sm.t.A[(rbase + m * 16) * 32 + koff];
        #pragma unroll
        for (int n = 0; n < 4; ++n)
            bg[n] = *(const bf16x8*)&sm.t.B[(cbase + n * 16) * 32 + koff];
        #pragma unroll
        for (int m = 0; m < 4; ++m)
            #pragma unroll
            for (int n = 0; n < 4; ++n)
                acc[m][n] = __builtin_amdgcn_mfma_f32_16x16x32_bf16(
                    af[m], bg[n], acc[m][n], 0, 0, 0);
    }

    // ---- epilogue: per-row top-2 (approx keys) ----
    u64 bk1[16], bk2[16];
    #pragma unroll
    for (int s = 0; s < 16; ++s) { bk1[s] = ~0ull; bk2[s] = ~0ull; }

    #pragma unroll
    for (int n = 0; n < 4; ++n) {
        const int col = wc * 64 + n * 16 + (lane & 15);
        const float cc = c2f[code0 + col];
        const u64 bin = (u64)((code0 + col) & 1023);
        #pragma unroll
        for (int m = 0; m < 4; ++m)
            #pragma unroll
            for (int r = 0; r < 4; ++r) {
                const float sc = cc - 2.0f * acc[m][n][r];
                const u64 key = ((u64)mapf(sc) << 10) | bin;
                const int s = m * 4 + r;
                if (key < bk1[s]) { bk2[s] = bk1[s]; bk1[s] = key; }
                else if (key < bk2[s]) bk2[s] = key;
            }
    }

    // 2-step shfl merge across lane bits 0..1 (16 cols per surviving lane)
    #pragma unroll
    for (int s = 0; s < 16; ++s) {
        #pragma unroll
        for (int mask = 1; mask <= 2; mask <<= 1) {
            const u64 o1 = __shfl_xor(bk1[s], mask, 64);
            const u64 o2 = __shfl_xor(bk2[s], mask, 64);
            const u64 hi = bk1[s] > o1 ? bk1[s] : o1;
            bk1[s] = bk1[s] < o1 ? bk1[s] : o1;
            const u64 lo2 = o2 < bk2[s] ? o2 : bk2[s];
            bk2[s] = hi < lo2 ? hi : lo2;
        }
    }

    __syncthreads();   // tiles no longer needed; red aliases them

    if ((lane & 3) == 0) {
        const int jj = wc * 8 + ((lane >> 2) & 3) * 2;
        #pragma unroll
        for (int s = 0; s < 16; ++s) {
            const int row = wr * 64 + (s >> 2) * 16 + (lane >> 4) * 4 + (s & 3);
            sm.red[row][jj]     = bk1[s];
            sm.red[row][jj + 1] = bk2[s];
        }
    }
    __syncthreads();

    if (tid < 128) {
        u64 b1 = ~0ull, b2 = ~0ull;
        #pragma unroll
        for (int j = 0; j < 16; ++j) {
            const u64 k = sm.red[tid][j];
            if (k < b1) { b2 = b1; b1 = k; }
            else if (k < b2) b2 = k;
        }
        u64* dst = cand + ((size_t)ct * NROWS + n0 + tid) * 2;
        dst[0] = b1; dst[1] = b2;
    }
}

// ---------------- refine: global top2 merge + exact fp64 rescore ---------
// grid = 16384 rows; wave w handles q = {2w, 2w+1}
__global__ __launch_bounds__(256)
void refine_kernel(const u64* __restrict__ cand, const float* __restrict__ x_t,
                   const float* __restrict__ cb, const double* __restrict__ c2d,
                   float* __restrict__ idx_f, int* __restrict__ idx_i) {
    const int tid  = threadIdx.x;
    const int lane = tid & 63;
    const int w    = tid >> 6;
    const int row  = blockIdx.x;
    const float4 x4 = *(const float4*)(x_t + (size_t)row * C_ + lane * 4);
    #pragma unroll
    for (int t = 0; t < 2; ++t) {
        const int q = w * 2 + t;
        u64 key = ~0ull;
        if (lane < 16)
            key = cand[(((size_t)(q * 8 + (lane >> 1)) * NROWS) + row) * 2 + (lane & 1)];
        u64 b1 = key, b2 = ~0ull;
        #pragma unroll
        for (int mask = 1; mask <= 8; mask <<= 1) {
            const u64 o1 = __shfl_xor(b1, mask, 64);
            const u64 o2 = __shfl_xor(b2, mask, 64);
            const u64 hi = b1 > o1 ? b1 : o1;
            b1 = b1 < o1 ? b1 : o1;
            const u64 lo2 = o2 < b2 ? o2 : b2;
            b2 = hi < lo2 ? hi : lo2;
        }
        const int bin1 = (int)(__shfl(b1, 0, 64) & 1023ull);
        const int bin2 = (int)(__shfl(b2, 0, 64) & 1023ull);
        const float4 cA = *(const float4*)(cb + ((size_t)(q * BINS + bin1) * C_) + lane * 4);
        const float4 cB = *(const float4*)(cb + ((size_t)(q * BINS + bin2) * C_) + lane * 4);
        double d1 = (double)x4.x * cA.x + (double)x4.y * cA.y +
                    (double)x4.z * cA.z + (double)x4.w * cA.w;
        double d2 = (double)x4.x * cB.x + (double)x4.y * cB.y +
                    (double)x4.z * cB.z + (double)x4.w * cB.w;
        #pragma unroll
        for (int off = 32; off; off >>= 1) {
            d1 += __shfl_down(d1, off, 64);
            d2 += __shfl_down(d2, off, 64);
        }
        if (lane == 0) {
            const double s1 = c2d[q * BINS + bin1] - 2.0 * d1;
            const double s2 = c2d[q * BINS + bin2] - 2.0 * d2;
            int win;
            if (s1 < s2)      win = bin1;
            else if (s2 < s1) win = bin2;
            else              win = bin1 < bin2 ? bin1 : bin2;
            idx_f[(size_t)row * NQ + q] = (float)win;
            idx_i[(size_t)row * NQ + q] = win;
        }
    }
}

// ---------------- gather: q_ste output + loss ----------------------------
__global__ __launch_bounds__(256)
void gather_kernel(const float* __restrict__ x, const float* __restrict__ cb,
                   const int* __restrict__ idx_i, float* __restrict__ out,
                   float* __restrict__ loss) {
    __shared__ float ql[C_][17];
    const int blk = blockIdx.x;
    const int b   = blk >> 7;
    const int t0  = (blk & 127) << 4;
    const int tid = threadIdx.x;
    {
        const int c = tid;
        for (int nl = 0; nl < 16; ++nl) {
            const int n = b * T_ + t0 + nl;
            float acc = 0.f;
            #pragma unroll
            for (int qq = 0; qq < NQ; ++qq) {
                const int id = idx_i[(size_t)n * NQ + qq];
                acc += cb[((size_t)qq * BINS + id) * C_ + c];
            }
            ql[c][nl] = acc;
        }
    }
    __syncthreads();
    const int tx = tid & 15, ty = tid >> 4;
    float lsum = 0.f;
    for (int cg = 0; cg < 16; ++cg) {
        const int c = cg * 16 + ty;
        const size_t off = ((size_t)b * C_ + c) * T_ + t0 + tx;
        const float qv = ql[c][tx];
        const float xv = x[off];
        out[off] = qv;
        const float d = qv - xv;
        lsum += d * d;
    }
    #pragma unroll
    for (int off = 32; off; off >>= 1) lsum += __shfl_down(lsum, off, 64);
    if ((tid & 63) == 0)
        atomicAdd(loss, lsum * (2.0f / (float)(B_ * C_ * T_)));
}

extern "C" void kernel_launch(void* const* d_in, const int* in_sizes, int n_in,
                              void* d_out, int out_size, void* d_ws, size_t ws_size,
                              hipStream_t stream) {
    const float* x  = (const float*)d_in[0];
    const float* cb = (const float*)d_in[1];

    float* out   = (float*)d_out;
    float* idx_f = out + (size_t)B_ * C_ * T_;
    float* loss  = idx_f + (size_t)NROWS * NQ;

    char* ws = (char*)d_ws;
    bf16*   xs    = (bf16*)(ws + XS_OFF);
    bf16*   cs    = (bf16*)(ws + CS_OFF);
    float*  x_t   = (float*)(ws + XT_OFF);
    u64*    cand  = (u64*)(ws + CAND_OFF);
    double* c2d   = (double*)(ws + C2D_OFF);
    float*  c2f   = (float*)(ws + C2F_OFF);
    int*    idx_i = (int*)(ws + IDXI_OFF);

    hipMemsetAsync(loss, 0, sizeof(float), stream);
    prep_x<<<1024, 256, 0, stream>>>(x, x_t, xs);
    prep_cb<<<2048, 256, 0, stream>>>(cb, cs);
    c2_kernel<<<2048, 256, 0, stream>>>(cb, c2d, c2f);
    dist_kernel<<<8192, 256, 0, stream>>>(xs, cs, c2f, cand);
    refine_kernel<<<NROWS, 256, 0, stream>>>(cand, x_t, cb, c2d, idx_f, idx_i);
    gather_kernel<<<B_ * (T_ / 16), 256, 0, stream>>>(x, cb, idx_i, out, loss);
}

// Round 4
// 458.980 us; speedup vs baseline: 2.7844x; 2.7844x over previous
//
#include <hip/hip_runtime.h>

typedef unsigned long long u64;
typedef unsigned int u32;
typedef __bf16 bf16;
typedef bf16 bf16x8 __attribute__((ext_vector_type(8)));
typedef float f32x4 __attribute__((ext_vector_type(4)));

#define B_   8
#define C_   256
#define T_   2048
#define NQ   8
#define BINS 1024
#define NROWS (B_ * T_)          // 16384
#define NCODE (NQ * BINS)        // 8192
#define K3   768                 // 3 * C_  (x: hi,hi,lo | cb: hi,lo,hi)

// ---- workspace layout (bytes) ----
#define XS_OFF   ((size_t)0)                       // bf16 [16384][768]  = 25165824
#define CS_OFF   ((size_t)25165824)                // bf16 [8192][768]   = 12582912
#define XT_OFF   ((size_t)37748736)                // f32  [16384][256]  = 16777216
#define CAND_OFF ((size_t)54525952)                // u64  [64][16384][2]= 16777216
#define C2D_OFF  ((size_t)71303168)                // f64  [8192]        = 65536
#define C2F_OFF  ((size_t)71368704)                // f32  [8192]        = 32768
#define IDXI_OFF ((size_t)71401472)                // i32  [131072]      = 524288

static __device__ __forceinline__ void gll16(const void* g, void* l) {
    __builtin_amdgcn_global_load_lds(
        (const __attribute__((address_space(1))) u32*)g,
        (__attribute__((address_space(3))) u32*)l, 16, 0, 0);
}

static __device__ __forceinline__ u32 mapf(float f) {
    u32 u = __float_as_uint(f);
    return (u & 0x80000000u) ? ~u : (u | 0x80000000u);
}

// ---------------- prep_x: transpose + bf16 split -------------------------
__global__ __launch_bounds__(256)
void prep_x(const float* __restrict__ x, float* __restrict__ x_t,
            bf16* __restrict__ xs) {
    __shared__ float tile[64][65];
    const int tid = threadIdx.x;
    const int bid = blockIdx.x;
    const int b  = bid >> 7;
    const int c0 = ((bid >> 5) & 3) * 64;
    const int t0 = (bid & 31) * 64;
    {
        const int j = tid & 63, cg = tid >> 6;
        #pragma unroll
        for (int ii = 0; ii < 16; ++ii) {
            const int cl = cg * 16 + ii;
            tile[cl][j] = x[((size_t)(b * C_ + c0 + cl) * T_) + t0 + j];
        }
    }
    __syncthreads();
    {
        const int cl = tid & 63, tg = tid >> 6;
        #pragma unroll
        for (int jj = 0; jj < 16; ++jj) {
            const int tl = tg * 16 + jj;
            const float v = tile[cl][tl];
            const size_t n = (size_t)b * T_ + t0 + tl;
            x_t[n * C_ + c0 + cl] = v;
            const bf16 hi = (bf16)v;
            const bf16 lo = (bf16)(v - (float)hi);
            xs[n * K3 + c0 + cl]           = hi;   // block 0: hi
            xs[n * K3 + 256 + c0 + cl]     = hi;   // block 1: hi
            xs[n * K3 + 512 + c0 + cl]     = lo;   // block 2: lo
        }
    }
}

// ---------------- prep_cb: bf16 split of codebook [hi, lo, hi] -----------
struct alignas(8) BPack { bf16 v[4]; };
__global__ __launch_bounds__(256)
void prep_cb(const float* __restrict__ cb, bf16* __restrict__ cs) {
    const int lane = threadIdx.x & 63;
    const int w    = threadIdx.x >> 6;
    const int code = blockIdx.x * 4 + w;
    const float4 v = *(const float4*)(cb + (size_t)code * C_ + lane * 4);
    BPack hp, lp;
    float f[4] = {v.x, v.y, v.z, v.w};
    #pragma unroll
    for (int i = 0; i < 4; ++i) {
        hp.v[i] = (bf16)f[i];
        lp.v[i] = (bf16)(f[i] - (float)hp.v[i]);
    }
    bf16* base = cs + (size_t)code * K3 + lane * 4;
    *(BPack*)(base)       = hp;
    *(BPack*)(base + 256) = lp;
    *(BPack*)(base + 512) = hp;
}

// ---------------- c2: per-code squared norm (fp64 + fp32) ----------------
__global__ __launch_bounds__(256)
void c2_kernel(const float* __restrict__ cb, double* __restrict__ c2d,
               float* __restrict__ c2f) {
    const int w    = threadIdx.x >> 6;
    const int lane = threadIdx.x & 63;
    const int code = blockIdx.x * 4 + w;
    const float* row = cb + (size_t)code * C_;
    double s = 0.0;
    #pragma unroll
    for (int i = 0; i < C_ / 64; ++i) {
        const double v = (double)row[lane + i * 64];
        s += v * v;
    }
    #pragma unroll
    for (int off = 32; off; off >>= 1) s += __shfl_down(s, off, 64);
    if (lane == 0) { c2d[code] = s; c2f[code] = (float)s; }
}

// ---------------- dist: bf16 MFMA GEMM + per-block top2 ------------------
// grid = 64 coltiles * 128 rowtiles = 8192 blocks, 256 threads (4 waves 2x2)
// v2: LDS XOR-swizzle (T2, via pre-swizzled global source per rule #21) +
//     double-buffered staging with one barrier per K-step (T3 minimal).
//
// Swizzle (16B-slot units within each 8-row x 64B group):
//   phys_slot = logical_slot ^ (row & 7),  logical_slot = row*4 + g
//   read addr (bf16 elems): idx = (row*32 + koff) ^ ((row & 7) << 3)
//   gll16 writes linearly -> global SOURCE uses the inverse map per lane.
__global__ __launch_bounds__(256)
void dist_kernel(const bf16* __restrict__ xs, const bf16* __restrict__ cs,
                 const float* __restrict__ c2f, u64* __restrict__ cand) {
    union SM {
        struct { bf16 A[2][128 * 32]; bf16 B[2][128 * 32]; } t;   // 32 KB
        u64 red[128][17];                                         // 17.4 KB
    };
    __shared__ SM sm;

    const int tid  = threadIdx.x;
    const int lane = tid & 63;
    const int w    = tid >> 6;
    const int wr   = w >> 1, wc = w & 1;
    const int bid  = blockIdx.x;
    const int rt   = bid & 127;
    const int ct   = bid >> 7;
    const int n0   = rt * 128;
    const int code0 = ct * 128;

    f32x4 acc[4][4];
    #pragma unroll
    for (int m = 0; m < 4; ++m)
        #pragma unroll
        for (int n = 0; n < 4; ++n) {
            f32x4 z = {0.f, 0.f, 0.f, 0.f};
            acc[m][n] = z;
        }

    // ---- staging source: inverse-swizzled per-lane global offset ----
    // lane covers phys slot p in [0,32) of 8-row group (lane>>5), 16 rows/issue
    const int p   = lane & 31;
    const int grp = lane >> 5;
    const int p2  = (p >> 2) & 1, p3 = (p >> 3) & 1, p4 = (p >> 4) & 1;
    const int sr  = (p2 ^ p4) | (p3 << 1) | (p4 << 2);          // logical row&7
    const int sg  = ((p ^ p2 ^ p4) & 1) | ((((p >> 1) ^ p3) & 1) << 1); // slot
    const int srow = grp * 8 + sr;                               // 0..15
    const int soff = sg * 8;                                     // bf16 elems

    const bf16* gA0 = xs + (size_t)(n0 + w * 32 + srow) * K3 + soff;
    const bf16* gA1 = gA0 + (size_t)16 * K3;
    const bf16* gB0 = cs + (size_t)(code0 + w * 32 + srow) * K3 + soff;
    const bf16* gB1 = gB0 + (size_t)16 * K3;

    const int rbase = wr * 64 + (lane & 15);
    const int cbase = wc * 64 + (lane & 15);
    const int koff  = (lane >> 4) * 8;

    #define STAGE(buf, k0)                                         \
        do {                                                       \
            gll16(gA0 + (k0), &sm.t.A[buf][(w * 32) * 32]);        \
            gll16(gA1 + (k0), &sm.t.A[buf][(w * 32 + 16) * 32]);   \
            gll16(gB0 + (k0), &sm.t.B[buf][(w * 32) * 32]);        \
            gll16(gB1 + (k0), &sm.t.B[buf][(w * 32 + 16) * 32]);   \
        } while (0)

    STAGE(0, 0);
    __syncthreads();                       // vmcnt(0) drain + barrier

    for (int kt = 0; kt < K3 / 32; ++kt) {
        const int cur = kt & 1;
        if (kt < K3 / 32 - 1) STAGE(cur ^ 1, (kt + 1) * 32);   // prefetch

        bf16x8 af[4], bg[4];
        #pragma unroll
        for (int m = 0; m < 4; ++m) {
            const int R = rbase + m * 16;
            const int idx = (R * 32 + koff) ^ ((R & 7) << 3);
            af[m] = *(const bf16x8*)&sm.t.A[cur][idx];
        }
        #pragma unroll
        for (int n = 0; n < 4; ++n) {
            const int R = cbase + n * 16;
            const int idx = (R * 32 + koff) ^ ((R & 7) << 3);
            bg[n] = *(const bf16x8*)&sm.t.B[cur][idx];
        }
        #pragma unroll
        for (int m = 0; m < 4; ++m)
            #pragma unroll
            for (int n = 0; n < 4; ++n)
                acc[m][n] = __builtin_amdgcn_mfma_f32_16x16x32_bf16(
                    af[m], bg[n], acc[m][n], 0, 0, 0);

        __syncthreads();                   // drains prefetch; buf swap safe
    }
    #undef STAGE

    // ---- epilogue: per-row top-2 (approx keys), per-m to save VGPRs ----
    const int jj = wc * 8 + ((lane >> 2) & 3) * 2;
    #pragma unroll
    for (int m = 0; m < 4; ++m) {
        u64 k1[4], k2[4];
        #pragma unroll
        for (int r = 0; r < 4; ++r) { k1[r] = ~0ull; k2[r] = ~0ull; }
        #pragma unroll
        for (int n = 0; n < 4; ++n) {
            const int col = wc * 64 + n * 16 + (lane & 15);
            const float cc = c2f[code0 + col];
            const u64 bin = (u64)((code0 + col) & 1023);
            #pragma unroll
            for (int r = 0; r < 4; ++r) {
                const float sc = cc - 2.0f * acc[m][n][r];
                const u64 key = ((u64)mapf(sc) << 10) | bin;
                if (key < k1[r]) { k2[r] = k1[r]; k1[r] = key; }
                else if (key < k2[r]) k2[r] = key;
            }
        }
        #pragma unroll
        for (int r = 0; r < 4; ++r) {
            #pragma unroll
            for (int mask = 1; mask <= 2; mask <<= 1) {
                const u64 o1 = __shfl_xor(k1[r], mask, 64);
                const u64 o2 = __shfl_xor(k2[r], mask, 64);
                const u64 hi = k1[r] > o1 ? k1[r] : o1;
                k1[r] = k1[r] < o1 ? k1[r] : o1;
                const u64 lo2 = o2 < k2[r] ? o2 : k2[r];
                k2[r] = hi < lo2 ? hi : lo2;
            }
        }
        if ((lane & 3) == 0) {
            #pragma unroll
            for (int r = 0; r < 4; ++r) {
                const int row = wr * 64 + m * 16 + (lane >> 4) * 4 + r;
                sm.red[row][jj]     = k1[r];
                sm.red[row][jj + 1] = k2[r];
            }
        }
    }
    __syncthreads();

    if (tid < 128) {
        u64 b1 = ~0ull, b2 = ~0ull;
        #pragma unroll
        for (int j = 0; j < 16; ++j) {
            const u64 k = sm.red[tid][j];
            if (k < b1) { b2 = b1; b1 = k; }
            else if (k < b2) b2 = k;
        }
        u64* dst = cand + ((size_t)ct * NROWS + n0 + tid) * 2;
        dst[0] = b1; dst[1] = b2;
    }
}

// ---------------- refine: global top2 merge + exact fp64 rescore ---------
__global__ __launch_bounds__(256)
void refine_kernel(const u64* __restrict__ cand, const float* __restrict__ x_t,
                   const float* __restrict__ cb, const double* __restrict__ c2d,
                   float* __restrict__ idx_f, int* __restrict__ idx_i) {
    const int tid  = threadIdx.x;
    const int lane = tid & 63;
    const int w    = tid >> 6;
    const int row  = blockIdx.x;
    const float4 x4 = *(const float4*)(x_t + (size_t)row * C_ + lane * 4);
    #pragma unroll
    for (int t = 0; t < 2; ++t) {
        const int q = w * 2 + t;
        u64 key = ~0ull;
        if (lane < 16)
            key = cand[(((size_t)(q * 8 + (lane >> 1)) * NROWS) + row) * 2 + (lane & 1)];
        u64 b1 = key, b2 = ~0ull;
        #pragma unroll
        for (int mask = 1; mask <= 8; mask <<= 1) {
            const u64 o1 = __shfl_xor(b1, mask, 64);
            const u64 o2 = __shfl_xor(b2, mask, 64);
            const u64 hi = b1 > o1 ? b1 : o1;
            b1 = b1 < o1 ? b1 : o1;
            const u64 lo2 = o2 < b2 ? o2 : b2;
            b2 = hi < lo2 ? hi : lo2;
        }
        const int bin1 = (int)(__shfl(b1, 0, 64) & 1023ull);
        const int bin2 = (int)(__shfl(b2, 0, 64) & 1023ull);
        const float4 cA = *(const float4*)(cb + ((size_t)(q * BINS + bin1) * C_) + lane * 4);
        const float4 cB = *(const float4*)(cb + ((size_t)(q * BINS + bin2) * C_) + lane * 4);
        double d1 = (double)x4.x * cA.x + (double)x4.y * cA.y +
                    (double)x4.z * cA.z + (double)x4.w * cA.w;
        double d2 = (double)x4.x * cB.x + (double)x4.y * cB.y +
                    (double)x4.z * cB.z + (double)x4.w * cB.w;
        #pragma unroll
        for (int off = 32; off; off >>= 1) {
            d1 += __shfl_down(d1, off, 64);
            d2 += __shfl_down(d2, off, 64);
        }
        if (lane == 0) {
            const double s1 = c2d[q * BINS + bin1] - 2.0 * d1;
            const double s2 = c2d[q * BINS + bin2] - 2.0 * d2;
            int win;
            if (s1 < s2)      win = bin1;
            else if (s2 < s1) win = bin2;
            else              win = bin1 < bin2 ? bin1 : bin2;
            idx_f[(size_t)row * NQ + q] = (float)win;
            idx_i[(size_t)row * NQ + q] = win;
        }
    }
}

// ---------------- gather: q_ste output + loss ----------------------------
__global__ __launch_bounds__(256)
void gather_kernel(const float* __restrict__ x, const float* __restrict__ cb,
                   const int* __restrict__ idx_i, float* __restrict__ out,
                   float* __restrict__ loss) {
    __shared__ float ql[C_][17];
    const int blk = blockIdx.x;
    const int b   = blk >> 7;
    const int t0  = (blk & 127) << 4;
    const int tid = threadIdx.x;
    {
        const int c = tid;
        for (int nl = 0; nl < 16; ++nl) {
            const int n = b * T_ + t0 + nl;
            float acc = 0.f;
            #pragma unroll
            for (int qq = 0; qq < NQ; ++qq) {
                const int id = idx_i[(size_t)n * NQ + qq];
                acc += cb[((size_t)qq * BINS + id) * C_ + c];
            }
            ql[c][nl] = acc;
        }
    }
    __syncthreads();
    const int tx = tid & 15, ty = tid >> 4;
    float lsum = 0.f;
    for (int cg = 0; cg < 16; ++cg) {
        const int c = cg * 16 + ty;
        const size_t off = ((size_t)b * C_ + c) * T_ + t0 + tx;
        const float qv = ql[c][tx];
        const float xv = x[off];
        out[off] = qv;
        const float d = qv - xv;
        lsum += d * d;
    }
    #pragma unroll
    for (int off = 32; off; off >>= 1) lsum += __shfl_down(lsum, off, 64);
    if ((tid & 63) == 0)
        atomicAdd(loss, lsum * (2.0f / (float)(B_ * C_ * T_)));
}

extern "C" void kernel_launch(void* const* d_in, const int* in_sizes, int n_in,
                              void* d_out, int out_size, void* d_ws, size_t ws_size,
                              hipStream_t stream) {
    const float* x  = (const float*)d_in[0];
    const float* cb = (const float*)d_in[1];

    float* out   = (float*)d_out;
    float* idx_f = out + (size_t)B_ * C_ * T_;
    float* loss  = idx_f + (size_t)NROWS * NQ;

    char* ws = (char*)d_ws;
    bf16*   xs    = (bf16*)(ws + XS_OFF);
    bf16*   cs    = (bf16*)(ws + CS_OFF);
    float*  x_t   = (float*)(ws + XT_OFF);
    u64*    cand  = (u64*)(ws + CAND_OFF);
    double* c2d   = (double*)(ws + C2D_OFF);
    float*  c2f   = (float*)(ws + C2F_OFF);
    int*    idx_i = (int*)(ws + IDXI_OFF);

    hipMemsetAsync(loss, 0, sizeof(float), stream);
    prep_x<<<1024, 256, 0, stream>>>(x, x_t, xs);
    prep_cb<<<2048, 256, 0, stream>>>(cb, cs);
    c2_kernel<<<2048, 256, 0, stream>>>(cb, c2d, c2f);
    dist_kernel<<<8192, 256, 0, stream>>>(xs, cs, c2f, cand);
    refine_kernel<<<NROWS, 256, 0, stream>>>(cand, x_t, cb, c2d, idx_f, idx_i);
    gather_kernel<<<B_ * (T_ / 16), 256, 0, stream>>>(x, cb, idx_i, out, loss);
}

// Round 5
// 445.383 us; speedup vs baseline: 2.8694x; 1.0305x over previous
//
#include <hip/hip_runtime.h>

typedef unsigned long long u64;
typedef unsigned int u32;
typedef __bf16 bf16;
typedef bf16 bf16x8 __attribute__((ext_vector_type(8)));
typedef float f32x4 __attribute__((ext_vector_type(4)));

#define B_   8
#define C_   256
#define T_   2048
#define NQ   8
#define BINS 1024
#define NROWS (B_ * T_)          // 16384
#define NCODE (NQ * BINS)        // 8192
#define K3   768                 // 3 * C_  (x: hi,hi,lo | cb: hi,lo,hi)
#define NT   (K3 / 64)           // 12 K-tiles of 64

// ---- workspace layout (bytes) ----
#define XS_OFF   ((size_t)0)                       // bf16 [16384][768]  = 25165824
#define CS_OFF   ((size_t)25165824)                // bf16 [8192][768]   = 12582912
#define XT_OFF   ((size_t)37748736)                // f32  [16384][256]  = 16777216
#define CAND_OFF ((size_t)54525952)                // u64  [32][16384][2]=  8388608
#define C2D_OFF  ((size_t)71303168)                // f64  [8192]        = 65536
#define C2F_OFF  ((size_t)71368704)                // f32  [8192]        = 32768
#define IDXI_OFF ((size_t)71401472)                // i32  [131072]      = 524288

static __device__ __forceinline__ void gll16(const void* g, void* l) {
    __builtin_amdgcn_global_load_lds(
        (const __attribute__((address_space(1))) u32*)g,
        (__attribute__((address_space(3))) u32*)l, 16, 0, 0);
}

static __device__ __forceinline__ u32 mapf(float f) {
    u32 u = __float_as_uint(f);
    return (u & 0x80000000u) ? ~u : (u | 0x80000000u);
}

// ---------------- prep_x: transpose + bf16 split -------------------------
__global__ __launch_bounds__(256)
void prep_x(const float* __restrict__ x, float* __restrict__ x_t,
            bf16* __restrict__ xs) {
    __shared__ float tile[64][65];
    const int tid = threadIdx.x;
    const int bid = blockIdx.x;
    const int b  = bid >> 7;
    const int c0 = ((bid >> 5) & 3) * 64;
    const int t0 = (bid & 31) * 64;
    {
        const int j = tid & 63, cg = tid >> 6;
        #pragma unroll
        for (int ii = 0; ii < 16; ++ii) {
            const int cl = cg * 16 + ii;
            tile[cl][j] = x[((size_t)(b * C_ + c0 + cl) * T_) + t0 + j];
        }
    }
    __syncthreads();
    {
        const int cl = tid & 63, tg = tid >> 6;
        #pragma unroll
        for (int jj = 0; jj < 16; ++jj) {
            const int tl = tg * 16 + jj;
            const float v = tile[cl][tl];
            const size_t n = (size_t)b * T_ + t0 + tl;
            x_t[n * C_ + c0 + cl] = v;
            const bf16 hi = (bf16)v;
            const bf16 lo = (bf16)(v - (float)hi);
            xs[n * K3 + c0 + cl]           = hi;   // block 0: hi
            xs[n * K3 + 256 + c0 + cl]     = hi;   // block 1: hi
            xs[n * K3 + 512 + c0 + cl]     = lo;   // block 2: lo
        }
    }
}

// ---------------- prep_cb: bf16 split of codebook [hi, lo, hi] -----------
struct alignas(8) BPack { bf16 v[4]; };
__global__ __launch_bounds__(256)
void prep_cb(const float* __restrict__ cb, bf16* __restrict__ cs) {
    const int lane = threadIdx.x & 63;
    const int w    = threadIdx.x >> 6;
    const int code = blockIdx.x * 4 + w;
    const float4 v = *(const float4*)(cb + (size_t)code * C_ + lane * 4);
    BPack hp, lp;
    float f[4] = {v.x, v.y, v.z, v.w};
    #pragma unroll
    for (int i = 0; i < 4; ++i) {
        hp.v[i] = (bf16)f[i];
        lp.v[i] = (bf16)(f[i] - (float)hp.v[i]);
    }
    bf16* base = cs + (size_t)code * K3 + lane * 4;
    *(BPack*)(base)       = hp;
    *(BPack*)(base + 256) = lp;
    *(BPack*)(base + 512) = hp;
}

// ---------------- c2: per-code squared norm (fp64 + fp32) ----------------
__global__ __launch_bounds__(256)
void c2_kernel(const float* __restrict__ cb, double* __restrict__ c2d,
               float* __restrict__ c2f) {
    const int w    = threadIdx.x >> 6;
    const int lane = threadIdx.x & 63;
    const int code = blockIdx.x * 4 + w;
    const float* row = cb + (size_t)code * C_;
    double s = 0.0;
    #pragma unroll
    for (int i = 0; i < C_ / 64; ++i) {
        const double v = (double)row[lane + i * 64];
        s += v * v;
    }
    #pragma unroll
    for (int off = 32; off; off >>= 1) s += __shfl_down(s, off, 64);
    if (lane == 0) { c2d[code] = s; c2f[code] = (float)s; }
}

// ---------------- dist: 256x256 8-phase bf16 MFMA GEMM + top2 ------------
// grid = 2048 blocks (64 rt x 32 ct), 512 threads = 8 waves (2 wr x 4 wc).
// K = 768 = 12 tiles of BK=64. Per-wave output 128x64, split into 4
// quadrants (ah,bh) of 64x32; phase (ah,bh) reads ONLY A-half ah / B-half bh.
// Stage ring (1 half-tile = 2 gll16/thread per phase):
//   j0: A1(t+1)  j1: B1(t+1)  j2: A0(t+2)  j3: B0(t+2)
// Counted gates (before closing barrier): j0: vmcnt(6)  j1: vmcnt(10)
//   j3: vmcnt(8)   [last main iter: j3 -> vmcnt(4); tail tile j0 -> vmcnt(0)]
#define BARX() __builtin_amdgcn_s_barrier()
#define LGKM0() do { asm volatile("s_waitcnt lgkmcnt(0)" ::: "memory"); \
                     __builtin_amdgcn_sched_barrier(0); } while (0)
#define GATE(n) asm volatile("s_waitcnt vmcnt(" #n ")" ::: "memory")

__global__ __launch_bounds__(512)
void dist_kernel(const bf16* __restrict__ xs, const bf16* __restrict__ cs,
                 const float* __restrict__ c2f, u64* __restrict__ cand) {
    __shared__ bf16 As[2][2][128][64];   // [buf][half][row][k] 64 KB
    __shared__ bf16 Bs[2][2][128][64];   // 64 KB
    __shared__ u64 red[256][8];          // 16 KB

    const int tid  = threadIdx.x;
    const int lane = tid & 63;
    const int w    = tid >> 6;           // wave 0..7
    const int wr   = w >> 2;             // 0..1 (m)
    const int wc   = w & 3;              // 0..3 (n)
    const int bid  = blockIdx.x;
    const int swz  = ((bid & 7) << 8) | (bid >> 3);   // XCD swizzle (bijective)
    const int ct   = swz >> 6;           // 0..31  (256 codes each)
    const int rt   = swz & 63;           // 0..63  (256 rows each)
    const int n0   = rt * 256;
    const int code0 = ct * 256;

    // staging source: pre-swizzled global (rule #21); 8 rows per gll16
    const int l8   = lane >> 3;                       // row within 8-group
    const int sslt = (lane & 7) ^ l8;                 // swizzled 16B slot
    const bf16* pA = xs + (size_t)(n0 + w * 16 + l8) * K3 + sslt * 8;
    const bf16* pB = cs + (size_t)(code0 + w * 16 + l8) * K3 + sslt * 8;

    #define ISSUE_A(t, h)                                                   \
        do {                                                                \
            const bf16* s_ = pA + (size_t)(h) * 128 * K3 + (size_t)(t) * 64;\
            gll16(s_,              &As[(t) & 1][h][w * 16][0]);             \
            gll16(s_ + 8 * K3,     &As[(t) & 1][h][w * 16 + 8][0]);         \
        } while (0)
    #define ISSUE_B(t, h)                                                   \
        do {                                                                \
            const bf16* s_ = pB + (size_t)(h) * 128 * K3 + (size_t)(t) * 64;\
            gll16(s_,              &Bs[(t) & 1][h][w * 16][0]);             \
            gll16(s_ + 8 * K3,     &Bs[(t) & 1][h][w * 16 + 8][0]);         \
        } while (0)

    // frag read offsets (bytes within a [128][64] half region)
    const int c  = lane & 15;
    const int g  = lane >> 4;            // 0..3 k-chunk
    const int c7 = c & 7;
    const int aoff0 = (wr * 64 + c) * 128 + ((g) ^ c7) * 16;       // kk=0
    const int aoff1 = (wr * 64 + c) * 128 + ((4 + g) ^ c7) * 16;   // kk=1
    const int boff0 = (wc * 32 + c) * 128 + ((g) ^ c7) * 16;
    const int boff1 = (wc * 32 + c) * 128 + ((4 + g) ^ c7) * 16;

    bf16x8 af[4][2];
    bf16x8 bg[2][2][2];                  // [bh][n][kk]
    f32x4 acc[2][2][4][2];               // [ah][bh][m][n]
    #pragma unroll
    for (int ah = 0; ah < 2; ++ah)
        #pragma unroll
        for (int bh = 0; bh < 2; ++bh)
            #pragma unroll
            for (int m = 0; m < 4; ++m)
                #pragma unroll
                for (int n = 0; n < 2; ++n) {
                    f32x4 z = {0.f, 0.f, 0.f, 0.f};
                    acc[ah][bh][m][n] = z;
                }

    #define READ_A(b, h)                                                    \
        do {                                                                \
            const char* ba_ = (const char*)&As[b][h][0][0];                 \
            _Pragma("unroll")                                               \
            for (int m_ = 0; m_ < 4; ++m_) {                                \
                af[m_][0] = *(const bf16x8*)(ba_ + m_ * 2048 + aoff0);      \
                af[m_][1] = *(const bf16x8*)(ba_ + m_ * 2048 + aoff1);      \
            }                                                               \
        } while (0)
    #define READ_B(b, bh)                                                   \
        do {                                                                \
            const char* bb_ = (const char*)&Bs[b][bh][0][0];                \
            _Pragma("unroll")                                               \
            for (int n_ = 0; n_ < 2; ++n_) {                                \
                bg[bh][n_][0] = *(const bf16x8*)(bb_ + n_ * 2048 + boff0);  \
                bg[bh][n_][1] = *(const bf16x8*)(bb_ + n_ * 2048 + boff1);  \
            }                                                               \
        } while (0)
    #define MMA(ah, bh)                                                     \
        do {                                                                \
            __builtin_amdgcn_s_setprio(1);                                  \
            _Pragma("unroll")                                               \
            for (int m_ = 0; m_ < 4; ++m_)                                  \
                _Pragma("unroll")                                           \
                for (int n_ = 0; n_ < 2; ++n_) {                            \
                    acc[ah][bh][m_][n_] =                                   \
                        __builtin_amdgcn_mfma_f32_16x16x32_bf16(            \
                            af[m_][0], bg[bh][n_][0], acc[ah][bh][m_][n_],  \
                            0, 0, 0);                                       \
                    acc[ah][bh][m_][n_] =                                   \
                        __builtin_amdgcn_mfma_f32_16x16x32_bf16(            \
                            af[m_][1], bg[bh][n_][1], acc[ah][bh][m_][n_],  \
                            0, 0, 0);                                       \
                }                                                           \
            __builtin_amdgcn_s_setprio(0);                                  \
        } while (0)

    // ---- prologue: A0(0) B0(0) A1(0) B1(0) A0(1) B0(1) ----
    ISSUE_A(0, 0); ISSUE_B(0, 0);
    ISSUE_A(0, 1); ISSUE_B(0, 1);
    ISSUE_A(1, 0); ISSUE_B(1, 0);
    GATE(8);                              // A0(0), B0(0) landed
    BARX();

    #pragma unroll 1
    for (int t = 0; t < NT - 1; ++t) {
        const int b    = t & 1;
        const bool last = (t == NT - 2);
        // phase j0 (ah0, bh0)
        READ_A(b, 0);
        READ_B(b, 0);
        ISSUE_A(t + 1, 1);
        BARX(); LGKM0();
        MMA(0, 0);
        GATE(6);                          // B1(t) landed
        BARX();
        // phase j1 (ah0, bh1)
        READ_B(b, 1);
        ISSUE_B(t + 1, 1);
        BARX(); LGKM0();
        MMA(0, 1);
        GATE(10);                         // A1(t) landed
        BARX();
        // phase j2 (ah1, bh0)
        READ_A(b, 1);
        if (!last) ISSUE_A(t + 2, 0);
        BARX(); LGKM0();
        MMA(1, 0);
        BARX();
        // phase j3 (ah1, bh1)
        if (!last) ISSUE_B(t + 2, 0);
        MMA(1, 1);
        if (last) { GATE(4); } else { GATE(8); }   // A0,B0(t+1) landed
        BARX();
    }

    // ---- tail tile NT-1 (no issues) ----
    {
        const int b = (NT - 1) & 1;
        READ_A(b, 0);
        READ_B(b, 0);
        BARX(); LGKM0();
        MMA(0, 0);
        GATE(0);                          // A1,B1(NT-1) landed
        BARX();
        READ_B(b, 1);
        BARX(); LGKM0();
        MMA(0, 1);
        BARX();
        READ_A(b, 1);
        BARX(); LGKM0();
        MMA(1, 0);
        MMA(1, 1);
    }
    #undef ISSUE_A
    #undef ISSUE_B
    #undef READ_A
    #undef READ_B
    #undef MMA

    // ---- epilogue: per-row top2 over this block's 256 codes ----
    #pragma unroll
    for (int ah = 0; ah < 2; ++ah)
        #pragma unroll
        for (int m = 0; m < 4; ++m) {
            u64 k1[4], k2[4];
            #pragma unroll
            for (int r = 0; r < 4; ++r) { k1[r] = ~0ull; k2[r] = ~0ull; }
            #pragma unroll
            for (int bh = 0; bh < 2; ++bh)
                #pragma unroll
                for (int n = 0; n < 2; ++n) {
                    const int code = code0 + bh * 128 + wc * 32 + n * 16 + c;
                    const float cc = c2f[code];
                    const u64 bin = (u64)(code & 1023);
                    #pragma unroll
                    for (int r = 0; r < 4; ++r) {
                        const float sc = cc - 2.0f * acc[ah][bh][m][n][r];
                        const u64 key = ((u64)mapf(sc) << 10) | bin;
                        if (key < k1[r]) { k2[r] = k1[r]; k1[r] = key; }
                        else if (key < k2[r]) k2[r] = key;
                    }
                }
            #pragma unroll
            for (int r = 0; r < 4; ++r) {
                #pragma unroll
                for (int mask = 1; mask <= 8; mask <<= 1) {
                    const u64 o1 = __shfl_xor(k1[r], mask, 64);
                    const u64 o2 = __shfl_xor(k2[r], mask, 64);
                    const u64 hi = k1[r] > o1 ? k1[r] : o1;
                    k1[r] = k1[r] < o1 ? k1[r] : o1;
                    const u64 lo2 = o2 < k2[r] ? o2 : k2[r];
                    k2[r] = hi < lo2 ? hi : lo2;
                }
            }
            if (c == 0) {
                #pragma unroll
                for (int r = 0; r < 4; ++r) {
                    const int rowt = ah * 128 + wr * 64 + m * 16 + g * 4 + r;
                    red[rowt][wc * 2]     = k1[r];
                    red[rowt][wc * 2 + 1] = k2[r];
                }
            }
        }
    __syncthreads();

    if (tid < 256) {
        u64 b1 = ~0ull, b2 = ~0ull;
        #pragma unroll
        for (int j = 0; j < 8; ++j) {
            const u64 k = red[tid][j];
            if (k < b1) { b2 = b1; b1 = k; }
            else if (k < b2) b2 = k;
        }
        u64* dst = cand + ((size_t)ct * NROWS + n0 + tid) * 2;
        dst[0] = b1; dst[1] = b2;
    }
}

// ---------------- refine: global top2 merge + exact fp64 rescore ---------
// grid = 16384 rows; wave w handles q = {2w, 2w+1}; 4 ct-blocks per q
__global__ __launch_bounds__(256)
void refine_kernel(const u64* __restrict__ cand, const float* __restrict__ x_t,
                   const float* __restrict__ cb, const double* __restrict__ c2d,
                   float* __restrict__ idx_f, int* __restrict__ idx_i) {
    const int tid  = threadIdx.x;
    const int lane = tid & 63;
    const int w    = tid >> 6;
    const int row  = blockIdx.x;
    const float4 x4 = *(const float4*)(x_t + (size_t)row * C_ + lane * 4);
    #pragma unroll
    for (int t = 0; t < 2; ++t) {
        const int q = w * 2 + t;
        u64 key = ~0ull;
        if (lane < 8)
            key = cand[(((size_t)(q * 4 + (lane >> 1)) * NROWS) + row) * 2 + (lane & 1)];
        u64 b1 = key, b2 = ~0ull;
        #pragma unroll
        for (int mask = 1; mask <= 4; mask <<= 1) {
            const u64 o1 = __shfl_xor(b1, mask, 64);
            const u64 o2 = __shfl_xor(b2, mask, 64);
            const u64 hi = b1 > o1 ? b1 : o1;
            b1 = b1 < o1 ? b1 : o1;
            const u64 lo2 = o2 < b2 ? o2 : b2;
            b2 = hi < lo2 ? hi : lo2;
        }
        const int bin1 = (int)(__shfl(b1, 0, 64) & 1023ull);
        const int bin2 = (int)(__shfl(b2, 0, 64) & 1023ull);
        const float4 cA = *(const float4*)(cb + ((size_t)(q * BINS + bin1) * C_) + lane * 4);
        const float4 cB = *(const float4*)(cb + ((size_t)(q * BINS + bin2) * C_) + lane * 4);
        double d1 = (double)x4.x * cA.x + (double)x4.y * cA.y +
                    (double)x4.z * cA.z + (double)x4.w * cA.w;
        double d2 = (double)x4.x * cB.x + (double)x4.y * cB.y +
                    (double)x4.z * cB.z + (double)x4.w * cB.w;
        #pragma unroll
        for (int off = 32; off; off >>= 1) {
            d1 += __shfl_down(d1, off, 64);
            d2 += __shfl_down(d2, off, 64);
        }
        if (lane == 0) {
            const double s1 = c2d[q * BINS + bin1] - 2.0 * d1;
            const double s2 = c2d[q * BINS + bin2] - 2.0 * d2;
            int win;
            if (s1 < s2)      win = bin1;
            else if (s2 < s1) win = bin2;
            else              win = bin1 < bin2 ? bin1 : bin2;
            idx_f[(size_t)row * NQ + q] = (float)win;
            idx_i[(size_t)row * NQ + q] = win;
        }
    }
}

// ---------------- gather: q_ste output + loss ----------------------------
__global__ __launch_bounds__(256)
void gather_kernel(const float* __restrict__ x, const float* __restrict__ cb,
                   const int* __restrict__ idx_i, float* __restrict__ out,
                   float* __restrict__ loss) {
    __shared__ float ql[C_][17];
    const int blk = blockIdx.x;
    const int b   = blk >> 7;
    const int t0  = (blk & 127) << 4;
    const int tid = threadIdx.x;
    {
        const int c = tid;
        for (int nl = 0; nl < 16; ++nl) {
            const int n = b * T_ + t0 + nl;
            float acc = 0.f;
            #pragma unroll
            for (int qq = 0; qq < NQ; ++qq) {
                const int id = idx_i[(size_t)n * NQ + qq];
                acc += cb[((size_t)qq * BINS + id) * C_ + c];
            }
            ql[c][nl] = acc;
        }
    }
    __syncthreads();
    const int tx = tid & 15, ty = tid >> 4;
    float lsum = 0.f;
    for (int cg = 0; cg < 16; ++cg) {
        const int c = cg * 16 + ty;
        const size_t off = ((size_t)b * C_ + c) * T_ + t0 + tx;
        const float qv = ql[c][tx];
        const float xv = x[off];
        out[off] = qv;
        const float d = qv - xv;
        lsum += d * d;
    }
    #pragma unroll
    for (int off = 32; off; off >>= 1) lsum += __shfl_down(lsum, off, 64);
    if ((tid & 63) == 0)
        atomicAdd(loss, lsum * (2.0f / (float)(B_ * C_ * T_)));
}

extern "C" void kernel_launch(void* const* d_in, const int* in_sizes, int n_in,
                              void* d_out, int out_size, void* d_ws, size_t ws_size,
                              hipStream_t stream) {
    const float* x  = (const float*)d_in[0];
    const float* cb = (const float*)d_in[1];

    float* out   = (float*)d_out;
    float* idx_f = out + (size_t)B_ * C_ * T_;
    float* loss  = idx_f + (size_t)NROWS * NQ;

    char* ws = (char*)d_ws;
    bf16*   xs    = (bf16*)(ws + XS_OFF);
    bf16*   cs    = (bf16*)(ws + CS_OFF);
    float*  x_t   = (float*)(ws + XT_OFF);
    u64*    cand  = (u64*)(ws + CAND_OFF);
    double* c2d   = (double*)(ws + C2D_OFF);
    float*  c2f   = (float*)(ws + C2F_OFF);
    int*    idx_i = (int*)(ws + IDXI_OFF);

    hipMemsetAsync(loss, 0, sizeof(float), stream);
    prep_x<<<1024, 256, 0, stream>>>(x, x_t, xs);
    prep_cb<<<2048, 256, 0, stream>>>(cb, cs);
    c2_kernel<<<2048, 256, 0, stream>>>(cb, c2d, c2f);
    dist_kernel<<<2048, 512, 0, stream>>>(xs, cs, c2f, cand);
    refine_kernel<<<NROWS, 256, 0, stream>>>(cand, x_t, cb, c2d, idx_f, idx_i);
    gather_kernel<<<B_ * (T_ / 16), 256, 0, stream>>>(x, cb, idx_i, out, loss);
}

// Round 6
// 410.216 us; speedup vs baseline: 3.1154x; 1.0857x over previous
//
#include <hip/hip_runtime.h>

typedef unsigned long long u64;
typedef unsigned int u32;
typedef _Float16 f16;
typedef f16 f16x8 __attribute__((ext_vector_type(8)));
typedef float f32x4 __attribute__((ext_vector_type(4)));

#define B_   8
#define C_   256
#define T_   2048
#define NQ   8
#define BINS 1024
#define NROWS (B_ * T_)          // 16384
#define NCODE (NQ * BINS)        // 8192
#define KA   512                 // A: [xh | xl]  (fp16 limbs, exact x)
#define KB   256                 // B: single fp16 limb ch, read wrapped
#define NT   (KA / 64)           // 8 K-tiles of 64

// ---- workspace layout (bytes) ----
#define XS_OFF   ((size_t)0)                       // f16 [16384][512]   = 16777216
#define CS_OFF   ((size_t)16777216)                // f16 [8192][256]    =  4194304
#define XT_OFF   ((size_t)20971520)                // f32 [16384][256]   = 16777216
#define CAND_OFF ((size_t)37748736)                // u64 [32][16384][2] =  8388608
#define C2D_OFF  ((size_t)46137344)                // f64 [8192]         =    65536
#define C2F_OFF  ((size_t)46202880)                // f32 [8192]         =    32768
#define IDXI_OFF ((size_t)46235648)                // i32 [131072]       =   524288

static __device__ __forceinline__ void gll16(const void* g, void* l) {
    __builtin_amdgcn_global_load_lds(
        (const __attribute__((address_space(1))) u32*)g,
        (__attribute__((address_space(3))) u32*)l, 16, 0, 0);
}

static __device__ __forceinline__ u32 mapf(float f) {
    u32 u = __float_as_uint(f);
    return (u & 0x80000000u) ? ~u : (u | 0x80000000u);
}

// ---------------- prep_x: transpose + exact fp16 2-limb split ------------
__global__ __launch_bounds__(256)
void prep_x(const float* __restrict__ x, float* __restrict__ x_t,
            f16* __restrict__ xs) {
    __shared__ float tile[64][65];
    const int tid = threadIdx.x;
    const int bid = blockIdx.x;
    const int b  = bid >> 7;
    const int c0 = ((bid >> 5) & 3) * 64;
    const int t0 = (bid & 31) * 64;
    {
        const int j = tid & 63, cg = tid >> 6;
        #pragma unroll
        for (int ii = 0; ii < 16; ++ii) {
            const int cl = cg * 16 + ii;
            tile[cl][j] = x[((size_t)(b * C_ + c0 + cl) * T_) + t0 + j];
        }
    }
    __syncthreads();
    {
        const int cl = tid & 63, tg = tid >> 6;
        #pragma unroll
        for (int jj = 0; jj < 16; ++jj) {
            const int tl = tg * 16 + jj;
            const float v = tile[cl][tl];
            const size_t n = (size_t)b * T_ + t0 + tl;
            x_t[n * C_ + c0 + cl] = v;
            const f16 hi = (f16)v;
            const f16 lo = (f16)(v - (float)hi);
            xs[n * KA + c0 + cl]       = hi;   // limb 0: hi
            xs[n * KA + 256 + c0 + cl] = lo;   // limb 1: lo
        }
    }
}

// ---------------- prep_cb_c2: fp16 codebook + exact norms ----------------
struct alignas(8) H4 { f16 v[4]; };
__global__ __launch_bounds__(256)
void prep_cb_c2(const float* __restrict__ cb, f16* __restrict__ cs,
                double* __restrict__ c2d, float* __restrict__ c2f) {
    const int w    = threadIdx.x >> 6;
    const int lane = threadIdx.x & 63;
    const int code = blockIdx.x * 4 + w;
    const float4 v = *(const float4*)(cb + (size_t)code * C_ + lane * 4);
    H4 h;
    h.v[0] = (f16)v.x; h.v[1] = (f16)v.y; h.v[2] = (f16)v.z; h.v[3] = (f16)v.w;
    *(H4*)(cs + (size_t)code * KB + lane * 4) = h;
    double s = (double)v.x * v.x + (double)v.y * v.y +
               (double)v.z * v.z + (double)v.w * v.w;
    #pragma unroll
    for (int off = 32; off; off >>= 1) s += __shfl_down(s, off, 64);
    if (lane == 0) { c2d[code] = s; c2f[code] = (float)s; }
}

// ---------------- dist: 256x256 8-phase f16 MFMA GEMM + top2 -------------
// grid = 2048 blocks (64 rt x 32 ct), 512 threads = 8 waves (2 wr x 4 wc).
// K = 512 = 8 tiles of BK=64. A = xs (stride 512); B = cs (stride 256),
// K-index wrapped mod 256 ((t&3)*64) -> B limbs [ch,ch] without duplication.
// XCD scan order: ct-inner (4 per XCD) / rt-outer -> concurrent working set
// (8 A-tiles + 4 B-tiles ~ 2.6 MB) fits per-XCD L2.
#define BARX() __builtin_amdgcn_s_barrier()
#define LGKM0() do { asm volatile("s_waitcnt lgkmcnt(0)" ::: "memory"); \
                     __builtin_amdgcn_sched_barrier(0); } while (0)
#define GATE(n) asm volatile("s_waitcnt vmcnt(" #n ")" ::: "memory")

__global__ __launch_bounds__(512)
void dist_kernel(const f16* __restrict__ xs, const f16* __restrict__ cs,
                 const float* __restrict__ c2f, u64* __restrict__ cand) {
    __shared__ f16 As[2][2][128][64];    // [buf][half][row][k] 64 KB
    __shared__ f16 Bs[2][2][128][64];    // 64 KB
    __shared__ u64 red[256][8];          // 16 KB

    const int tid  = threadIdx.x;
    const int lane = tid & 63;
    const int w    = tid >> 6;           // wave 0..7
    const int wr   = w >> 2;             // 0..1 (m)
    const int wc   = w & 3;              // 0..3 (n)
    const int bid  = blockIdx.x;
    const int xcd  = bid & 7;
    const int j    = bid >> 3;           // 0..255
    const int ct   = xcd * 4 + (j & 3);  // 0..31 (4 cts per XCD, inner)
    const int rt   = j >> 2;             // 0..63 (outer)
    const int n0   = rt * 256;
    const int code0 = ct * 256;

    // staging source: pre-swizzled global (rule #21); 8 rows per gll16
    const int l8   = lane >> 3;                       // row within 8-group
    const int sslt = (lane & 7) ^ l8;                 // swizzled 16B slot
    const f16* pA = xs + (size_t)(n0 + w * 16 + l8) * KA + sslt * 8;
    const f16* pB = cs + (size_t)(code0 + w * 16 + l8) * KB + sslt * 8;

    #define ISSUE_A(t, h)                                                   \
        do {                                                                \
            const f16* s_ = pA + (size_t)(h) * 128 * KA + (size_t)(t) * 64; \
            gll16(s_,          &As[(t) & 1][h][w * 16][0]);                 \
            gll16(s_ + 8 * KA, &As[(t) & 1][h][w * 16 + 8][0]);             \
        } while (0)
    #define ISSUE_B(t, h)                                                   \
        do {                                                                \
            const f16* s_ = pB + (size_t)(h) * 128 * KB                     \
                               + (size_t)((t) & 3) * 64;                    \
            gll16(s_,          &Bs[(t) & 1][h][w * 16][0]);                 \
            gll16(s_ + 8 * KB, &Bs[(t) & 1][h][w * 16 + 8][0]);             \
        } while (0)

    // frag read offsets (bytes within a [128][64] half region)
    const int c  = lane & 15;
    const int g  = lane >> 4;            // 0..3 k-chunk
    const int c7 = c & 7;
    const int aoff0 = (wr * 64 + c) * 128 + ((g) ^ c7) * 16;       // kk=0
    const int aoff1 = (wr * 64 + c) * 128 + ((4 + g) ^ c7) * 16;   // kk=1
    const int boff0 = (wc * 32 + c) * 128 + ((g) ^ c7) * 16;
    const int boff1 = (wc * 32 + c) * 128 + ((4 + g) ^ c7) * 16;

    f16x8 af[4][2];
    f16x8 bg[2][2][2];                   // [bh][n][kk]
    f32x4 acc[2][2][4][2];               // [ah][bh][m][n]
    #pragma unroll
    for (int ah = 0; ah < 2; ++ah)
        #pragma unroll
        for (int bh = 0; bh < 2; ++bh)
            #pragma unroll
            for (int m = 0; m < 4; ++m)
                #pragma unroll
                for (int n = 0; n < 2; ++n) {
                    f32x4 z = {0.f, 0.f, 0.f, 0.f};
                    acc[ah][bh][m][n] = z;
                }

    #define READ_A(b, h)                                                    \
        do {                                                                \
            const char* ba_ = (const char*)&As[b][h][0][0];                 \
            _Pragma("unroll")                                               \
            for (int m_ = 0; m_ < 4; ++m_) {                                \
                af[m_][0] = *(const f16x8*)(ba_ + m_ * 2048 + aoff0);       \
                af[m_][1] = *(const f16x8*)(ba_ + m_ * 2048 + aoff1);       \
            }                                                               \
        } while (0)
    #define READ_B(b, bh)                                                   \
        do {                                                                \
            const char* bb_ = (const char*)&Bs[b][bh][0][0];                \
            _Pragma("unroll")                                               \
            for (int n_ = 0; n_ < 2; ++n_) {                                \
                bg[bh][n_][0] = *(const f16x8*)(bb_ + n_ * 2048 + boff0);   \
                bg[bh][n_][1] = *(const f16x8*)(bb_ + n_ * 2048 + boff1);   \
            }                                                               \
        } while (0)
    #define MMA(ah, bh)                                                     \
        do {                                                                \
            __builtin_amdgcn_s_setprio(1);                                  \
            _Pragma("unroll")                                               \
            for (int m_ = 0; m_ < 4; ++m_)                                  \
                _Pragma("unroll")                                           \
                for (int n_ = 0; n_ < 2; ++n_) {                            \
                    acc[ah][bh][m_][n_] =                                   \
                        __builtin_amdgcn_mfma_f32_16x16x32_f16(             \
                            af[m_][0], bg[bh][n_][0], acc[ah][bh][m_][n_],  \
                            0, 0, 0);                                       \
                    acc[ah][bh][m_][n_] =                                   \
                        __builtin_amdgcn_mfma_f32_16x16x32_f16(             \
                            af[m_][1], bg[bh][n_][1], acc[ah][bh][m_][n_],  \
                            0, 0, 0);                                       \
                }                                                           \
            __builtin_amdgcn_s_setprio(0);                                  \
        } while (0)

    // ---- prologue: A0(0) B0(0) A1(0) B1(0) A0(1) B0(1) ----
    ISSUE_A(0, 0); ISSUE_B(0, 0);
    ISSUE_A(0, 1); ISSUE_B(0, 1);
    ISSUE_A(1, 0); ISSUE_B(1, 0);
    GATE(8);                              // A0(0), B0(0) landed
    BARX();

    #pragma unroll 1
    for (int t = 0; t < NT - 1; ++t) {
        const int b    = t & 1;
        const bool last = (t == NT - 2);
        // phase j0 (ah0, bh0)
        READ_A(b, 0);
        READ_B(b, 0);
        ISSUE_A(t + 1, 1);
        BARX(); LGKM0();
        MMA(0, 0);
        GATE(6);                          // A1(t), B1(t) landed
        BARX();
        // phase j1 (ah0, bh1)
        READ_B(b, 1);
        ISSUE_B(t + 1, 1);
        BARX(); LGKM0();
        MMA(0, 1);
        GATE(10);                         // (vacuous in steady state)
        BARX();
        // phase j2 (ah1, bh0)
        READ_A(b, 1);
        if (!last) ISSUE_A(t + 2, 0);
        BARX(); LGKM0();
        MMA(1, 0);
        BARX();
        // phase j3 (ah1, bh1)
        if (!last) ISSUE_B(t + 2, 0);
        MMA(1, 1);
        if (last) { GATE(4); } else { GATE(8); }   // A0,B0(t+1) landed
        BARX();
    }

    // ---- tail tile NT-1 (no issues) ----
    {
        const int b = (NT - 1) & 1;
        READ_A(b, 0);
        READ_B(b, 0);
        BARX(); LGKM0();
        MMA(0, 0);
        GATE(0);                          // A1,B1(NT-1) landed
        BARX();
        READ_B(b, 1);
        BARX(); LGKM0();
        MMA(0, 1);
        BARX();
        READ_A(b, 1);
        BARX(); LGKM0();
        MMA(1, 0);
        MMA(1, 1);
    }
    #undef ISSUE_A
    #undef ISSUE_B
    #undef READ_A
    #undef READ_B
    #undef MMA

    // ---- epilogue: per-row top2 over this block's 256 codes ----
    #pragma unroll
    for (int ah = 0; ah < 2; ++ah)
        #pragma unroll
        for (int m = 0; m < 4; ++m) {
            u64 k1[4], k2[4];
            #pragma unroll
            for (int r = 0; r < 4; ++r) { k1[r] = ~0ull; k2[r] = ~0ull; }
            #pragma unroll
            for (int bh = 0; bh < 2; ++bh)
                #pragma unroll
                for (int n = 0; n < 2; ++n) {
                    const int code = code0 + bh * 128 + wc * 32 + n * 16 + c;
                    const float cc = c2f[code];
                    const u64 bin = (u64)(code & 1023);
                    #pragma unroll
                    for (int r = 0; r < 4; ++r) {
                        const float sc = cc - 2.0f * acc[ah][bh][m][n][r];
                        const u64 key = ((u64)mapf(sc) << 10) | bin;
                        if (key < k1[r]) { k2[r] = k1[r]; k1[r] = key; }
                        else if (key < k2[r]) k2[r] = key;
                    }
                }
            #pragma unroll
            for (int r = 0; r < 4; ++r) {
                #pragma unroll
                for (int mask = 1; mask <= 8; mask <<= 1) {
                    const u64 o1 = __shfl_xor(k1[r], mask, 64);
                    const u64 o2 = __shfl_xor(k2[r], mask, 64);
                    const u64 hi = k1[r] > o1 ? k1[r] : o1;
                    k1[r] = k1[r] < o1 ? k1[r] : o1;
                    const u64 lo2 = o2 < k2[r] ? o2 : k2[r];
                    k2[r] = hi < lo2 ? hi : lo2;
                }
            }
            if (c == 0) {
                #pragma unroll
                for (int r = 0; r < 4; ++r) {
                    const int rowt = ah * 128 + wr * 64 + m * 16 + g * 4 + r;
                    red[rowt][wc * 2]     = k1[r];
                    red[rowt][wc * 2 + 1] = k2[r];
                }
            }
        }
    __syncthreads();

    if (tid < 256) {
        u64 b1 = ~0ull, b2 = ~0ull;
        #pragma unroll
        for (int jj = 0; jj < 8; ++jj) {
            const u64 k = red[tid][jj];
            if (k < b1) { b2 = b1; b1 = k; }
            else if (k < b2) b2 = k;
        }
        u64* dst = cand + ((size_t)ct * NROWS + n0 + tid) * 2;
        dst[0] = b1; dst[1] = b2;
    }
}

// ---------------- refine: merge 8 cands -> top4 -> exact fp64 rescore ----
// grid = 16384 rows; wave w handles q = {2w, 2w+1}
__global__ __launch_bounds__(256)
void refine_kernel(const u64* __restrict__ cand, const float* __restrict__ x_t,
                   const float* __restrict__ cb, const double* __restrict__ c2d,
                   float* __restrict__ idx_f, int* __restrict__ idx_i) {
    const int tid  = threadIdx.x;
    const int lane = tid & 63;
    const int w    = tid >> 6;
    const int row  = blockIdx.x;
    const float4 x4 = *(const float4*)(x_t + (size_t)row * C_ + lane * 4);
    #pragma unroll
    for (int t = 0; t < 2; ++t) {
        const int q = w * 2 + t;
        u64 key = ~0ull;
        if (lane < 8)
            key = cand[(((size_t)(q * 4 + (lane >> 1)) * NROWS) + row) * 2 + (lane & 1)];
        // all lanes build the top-4 of the 8 candidate keys
        u64 s0 = ~0ull, s1 = ~0ull, s2 = ~0ull, s3 = ~0ull;
        #pragma unroll
        for (int i = 0; i < 8; ++i) {
            const u64 k = __shfl(key, i, 64);
            if (k < s0)      { s3 = s2; s2 = s1; s1 = s0; s0 = k; }
            else if (k < s1) { s3 = s2; s2 = s1; s1 = k; }
            else if (k < s2) { s3 = s2; s2 = k; }
            else if (k < s3) { s3 = k; }
        }
        const int bins[4] = {(int)(s0 & 1023ull), (int)(s1 & 1023ull),
                             (int)(s2 & 1023ull), (int)(s3 & 1023ull)};
        double d[4];
        #pragma unroll
        for (int i = 0; i < 4; ++i) {
            const float4 cv =
                *(const float4*)(cb + ((size_t)(q * BINS + bins[i]) * C_) + lane * 4);
            d[i] = (double)x4.x * cv.x + (double)x4.y * cv.y +
                   (double)x4.z * cv.z + (double)x4.w * cv.w;
        }
        #pragma unroll
        for (int off = 32; off; off >>= 1)
            #pragma unroll
            for (int i = 0; i < 4; ++i) d[i] += __shfl_down(d[i], off, 64);
        if (lane == 0) {
            double best = 1e300;
            int win = BINS;
            #pragma unroll
            for (int i = 0; i < 4; ++i) {
                const double s = c2d[q * BINS + bins[i]] - 2.0 * d[i];
                if (s < best || (s == best && bins[i] < win)) {
                    best = s; win = bins[i];
                }
            }
            idx_f[(size_t)row * NQ + q] = (float)win;
            idx_i[(size_t)row * NQ + q] = win;
        }
    }
}

// ---------------- gather: q_ste output + loss ----------------------------
__global__ __launch_bounds__(256)
void gather_kernel(const float* __restrict__ x, const float* __restrict__ cb,
                   const int* __restrict__ idx_i, float* __restrict__ out,
                   float* __restrict__ loss) {
    __shared__ float ql[C_][17];
    const int blk = blockIdx.x;
    const int b   = blk >> 7;
    const int t0  = (blk & 127) << 4;
    const int tid = threadIdx.x;
    {
        const int c = tid;
        for (int nl = 0; nl < 16; ++nl) {
            const int n = b * T_ + t0 + nl;
            float acc = 0.f;
            #pragma unroll
            for (int qq = 0; qq < NQ; ++qq) {
                const int id = idx_i[(size_t)n * NQ + qq];
                acc += cb[((size_t)qq * BINS + id) * C_ + c];
            }
            ql[c][nl] = acc;
        }
    }
    __syncthreads();
    const int tx = tid & 15, ty = tid >> 4;
    float lsum = 0.f;
    for (int cg = 0; cg < 16; ++cg) {
        const int c = cg * 16 + ty;
        const size_t off = ((size_t)b * C_ + c) * T_ + t0 + tx;
        const float qv = ql[c][tx];
        const float xv = x[off];
        out[off] = qv;
        const float d = qv - xv;
        lsum += d * d;
    }
    #pragma unroll
    for (int off = 32; off; off >>= 1) lsum += __shfl_down(lsum, off, 64);
    if ((tid & 63) == 0)
        atomicAdd(loss, lsum * (2.0f / (float)(B_ * C_ * T_)));
}

extern "C" void kernel_launch(void* const* d_in, const int* in_sizes, int n_in,
                              void* d_out, int out_size, void* d_ws, size_t ws_size,
                              hipStream_t stream) {
    const float* x  = (const float*)d_in[0];
    const float* cb = (const float*)d_in[1];

    float* out   = (float*)d_out;
    float* idx_f = out + (size_t)B_ * C_ * T_;
    float* loss  = idx_f + (size_t)NROWS * NQ;

    char* ws = (char*)d_ws;
    f16*    xs    = (f16*)(ws + XS_OFF);
    f16*    cs    = (f16*)(ws + CS_OFF);
    float*  x_t   = (float*)(ws + XT_OFF);
    u64*    cand  = (u64*)(ws + CAND_OFF);
    double* c2d   = (double*)(ws + C2D_OFF);
    float*  c2f   = (float*)(ws + C2F_OFF);
    int*    idx_i = (int*)(ws + IDXI_OFF);

    hipMemsetAsync(loss, 0, sizeof(float), stream);
    prep_x<<<1024, 256, 0, stream>>>(x, x_t, xs);
    prep_cb_c2<<<2048, 256, 0, stream>>>(cb, cs, c2d, c2f);
    dist_kernel<<<2048, 512, 0, stream>>>(xs, cs, c2f, cand);
    refine_kernel<<<NROWS, 256, 0, stream>>>(cand, x_t, cb, c2d, idx_f, idx_i);
    gather_kernel<<<B_ * (T_ / 16), 256, 0, stream>>>(x, cb, idx_i, out, loss);
}

// Round 7
// 288.864 us; speedup vs baseline: 4.4242x; 1.4201x over previous
//
#include <hip/hip_runtime.h>

typedef unsigned long long u64;
typedef unsigned int u32;
typedef _Float16 f16;
typedef f16 f16x8 __attribute__((ext_vector_type(8)));
typedef float f32x4 __attribute__((ext_vector_type(4)));

#define B_   8
#define C_   256
#define T_   2048
#define NQ   8
#define BINS 1024
#define NROWS (B_ * T_)          // 16384
#define NCODE (NQ * BINS)        // 8192
#define KA   256                 // A: single fp16 limb xh
#define KB   256                 // B: single fp16 limb ch
#define NT   (KA / 64)           // 4 K-tiles of 64

// ---- workspace layout (bytes) ----
#define XS_OFF   ((size_t)0)                       // f16 [16384][256]   =  8388608
#define CS_OFF   ((size_t)8388608)                 // f16 [8192][256]    =  4194304
#define XT_OFF   ((size_t)12582912)                // f32 [16384][256]   = 16777216
#define CAND_OFF ((size_t)29360128)                // u64 [32][16384]    =  4194304
#define C2D_OFF  ((size_t)33554432)                // f64 [8192]         =    65536
#define C2F_OFF  ((size_t)33619968)                // f32 [8192]         =    32768
#define IDXI_OFF ((size_t)33652736)                // i32 [131072]       =   524288

static __device__ __forceinline__ void gll16(const void* g, void* l) {
    __builtin_amdgcn_global_load_lds(
        (const __attribute__((address_space(1))) u32*)g,
        (__attribute__((address_space(3))) u32*)l, 16, 0, 0);
}

static __device__ __forceinline__ u32 mapf(float f) {
    u32 u = __float_as_uint(f);
    return (u & 0x80000000u) ? ~u : (u | 0x80000000u);
}

// ---------------- prep_x: transpose + fp16 cast --------------------------
__global__ __launch_bounds__(256)
void prep_x(const float* __restrict__ x, float* __restrict__ x_t,
            f16* __restrict__ xs) {
    __shared__ float tile[64][65];
    const int tid = threadIdx.x;
    const int bid = blockIdx.x;
    const int b  = bid >> 7;
    const int c0 = ((bid >> 5) & 3) * 64;
    const int t0 = (bid & 31) * 64;
    {
        const int j = tid & 63, cg = tid >> 6;
        #pragma unroll
        for (int ii = 0; ii < 16; ++ii) {
            const int cl = cg * 16 + ii;
            tile[cl][j] = x[((size_t)(b * C_ + c0 + cl) * T_) + t0 + j];
        }
    }
    __syncthreads();
    {
        const int cl = tid & 63, tg = tid >> 6;
        #pragma unroll
        for (int jj = 0; jj < 16; ++jj) {
            const int tl = tg * 16 + jj;
            const float v = tile[cl][tl];
            const size_t n = (size_t)b * T_ + t0 + tl;
            x_t[n * C_ + c0 + cl] = v;
            xs[n * KA + c0 + cl]  = (f16)v;
        }
    }
}

// ---------------- prep_cb_c2: fp16 codebook + exact norms ----------------
struct alignas(8) H4 { f16 v[4]; };
__global__ __launch_bounds__(256)
void prep_cb_c2(const float* __restrict__ cb, f16* __restrict__ cs,
                double* __restrict__ c2d, float* __restrict__ c2f) {
    const int w    = threadIdx.x >> 6;
    const int lane = threadIdx.x & 63;
    const int code = blockIdx.x * 4 + w;
    const float4 v = *(const float4*)(cb + (size_t)code * C_ + lane * 4);
    H4 h;
    h.v[0] = (f16)v.x; h.v[1] = (f16)v.y; h.v[2] = (f16)v.z; h.v[3] = (f16)v.w;
    *(H4*)(cs + (size_t)code * KB + lane * 4) = h;
    double s = (double)v.x * v.x + (double)v.y * v.y +
               (double)v.z * v.z + (double)v.w * v.w;
    #pragma unroll
    for (int off = 32; off; off >>= 1) s += __shfl_down(s, off, 64);
    if (lane == 0) { c2d[code] = s; c2f[code] = (float)s; }
}

// ---------------- dist: 256x256 8-phase f16 MFMA GEMM + top2 -------------
// grid = 2048 blocks (64 rt x 32 ct), 512 threads = 8 waves (2 wr x 4 wc).
// K = 256 = 4 tiles of BK=64 (single fp16 limb; exact fp64 rescore of the
// merged top-4 in refine covers the ~6e-3 approx error; true gaps ~O(10)).
#define BARX() __builtin_amdgcn_s_barrier()
#define LGKM0() do { asm volatile("s_waitcnt lgkmcnt(0)" ::: "memory"); \
                     __builtin_amdgcn_sched_barrier(0); } while (0)
#define GATE(n) asm volatile("s_waitcnt vmcnt(" #n ")" ::: "memory")

__global__ __launch_bounds__(512)
void dist_kernel(const f16* __restrict__ xs, const f16* __restrict__ cs,
                 const float* __restrict__ c2f, u64* __restrict__ cand) {
    __shared__ f16 As[2][2][128][64];    // [buf][half][row][k] 64 KB
    __shared__ f16 Bs[2][2][128][64];    // 64 KB
    __shared__ u32 red[256][8];          // 8 KB

    const int tid  = threadIdx.x;
    const int lane = tid & 63;
    const int w    = tid >> 6;           // wave 0..7
    const int wr   = w >> 2;             // 0..1 (m)
    const int wc   = w & 3;              // 0..3 (n)
    const int bid  = blockIdx.x;
    const int xcd  = bid & 7;
    const int j    = bid >> 3;           // 0..255
    const int ct   = xcd * 4 + (j & 3);  // 0..31 (4 cts per XCD, inner)
    const int rt   = j >> 2;             // 0..63 (outer)
    const int n0   = rt * 256;
    const int code0 = ct * 256;

    // staging source: pre-swizzled global (rule #21); 8 rows per gll16
    const int l8   = lane >> 3;                       // row within 8-group
    const int sslt = (lane & 7) ^ l8;                 // swizzled 16B slot
    const f16* pA = xs + (size_t)(n0 + w * 16 + l8) * KA + sslt * 8;
    const f16* pB = cs + (size_t)(code0 + w * 16 + l8) * KB + sslt * 8;

    #define ISSUE_A(t, h)                                                   \
        do {                                                                \
            const f16* s_ = pA + (size_t)(h) * 128 * KA + (size_t)(t) * 64; \
            gll16(s_,          &As[(t) & 1][h][w * 16][0]);                 \
            gll16(s_ + 8 * KA, &As[(t) & 1][h][w * 16 + 8][0]);             \
        } while (0)
    #define ISSUE_B(t, h)                                                   \
        do {                                                                \
            const f16* s_ = pB + (size_t)(h) * 128 * KB + (size_t)(t) * 64; \
            gll16(s_,          &Bs[(t) & 1][h][w * 16][0]);                 \
            gll16(s_ + 8 * KB, &Bs[(t) & 1][h][w * 16 + 8][0]);             \
        } while (0)

    // frag read offsets (bytes within a [128][64] half region)
    const int c  = lane & 15;
    const int g  = lane >> 4;            // 0..3 k-chunk
    const int c7 = c & 7;
    const int aoff0 = (wr * 64 + c) * 128 + ((g) ^ c7) * 16;       // kk=0
    const int aoff1 = (wr * 64 + c) * 128 + ((4 + g) ^ c7) * 16;   // kk=1
    const int boff0 = (wc * 32 + c) * 128 + ((g) ^ c7) * 16;
    const int boff1 = (wc * 32 + c) * 128 + ((4 + g) ^ c7) * 16;

    f16x8 af[4][2];
    f16x8 bg[2][2][2];                   // [bh][n][kk]
    f32x4 acc[2][2][4][2];               // [ah][bh][m][n]
    #pragma unroll
    for (int ah = 0; ah < 2; ++ah)
        #pragma unroll
        for (int bh = 0; bh < 2; ++bh)
            #pragma unroll
            for (int m = 0; m < 4; ++m)
                #pragma unroll
                for (int n = 0; n < 2; ++n) {
                    f32x4 z = {0.f, 0.f, 0.f, 0.f};
                    acc[ah][bh][m][n] = z;
                }

    #define READ_A(b, h)                                                    \
        do {                                                                \
            const char* ba_ = (const char*)&As[b][h][0][0];                 \
            _Pragma("unroll")                                               \
            for (int m_ = 0; m_ < 4; ++m_) {                                \
                af[m_][0] = *(const f16x8*)(ba_ + m_ * 2048 + aoff0);       \
                af[m_][1] = *(const f16x8*)(ba_ + m_ * 2048 + aoff1);       \
            }                                                               \
        } while (0)
    #define READ_B(b, bh)                                                   \
        do {                                                                \
            const char* bb_ = (const char*)&Bs[b][bh][0][0];                \
            _Pragma("unroll")                                               \
            for (int n_ = 0; n_ < 2; ++n_) {                                \
                bg[bh][n_][0] = *(const f16x8*)(bb_ + n_ * 2048 + boff0);   \
                bg[bh][n_][1] = *(const f16x8*)(bb_ + n_ * 2048 + boff1);   \
            }                                                               \
        } while (0)
    #define MMA(ah, bh)                                                     \
        do {                                                                \
            __builtin_amdgcn_s_setprio(1);                                  \
            _Pragma("unroll")                                               \
            for (int m_ = 0; m_ < 4; ++m_)                                  \
                _Pragma("unroll")                                           \
                for (int n_ = 0; n_ < 2; ++n_) {                            \
                    acc[ah][bh][m_][n_] =                                   \
                        __builtin_amdgcn_mfma_f32_16x16x32_f16(             \
                            af[m_][0], bg[bh][n_][0], acc[ah][bh][m_][n_],  \
                            0, 0, 0);                                       \
                    acc[ah][bh][m_][n_] =                                   \
                        __builtin_amdgcn_mfma_f32_16x16x32_f16(             \
                            af[m_][1], bg[bh][n_][1], acc[ah][bh][m_][n_],  \
                            0, 0, 0);                                       \
                }                                                           \
            __builtin_amdgcn_s_setprio(0);                                  \
        } while (0)

    // ---- prologue: A0(0) B0(0) A1(0) B1(0) A0(1) B0(1) ----
    ISSUE_A(0, 0); ISSUE_B(0, 0);
    ISSUE_A(0, 1); ISSUE_B(0, 1);
    ISSUE_A(1, 0); ISSUE_B(1, 0);
    GATE(8);                              // A0(0), B0(0) landed
    BARX();

    #pragma unroll 1
    for (int t = 0; t < NT - 1; ++t) {
        const int b    = t & 1;
        const bool last = (t == NT - 2);
        // phase j0 (ah0, bh0)
        READ_A(b, 0);
        READ_B(b, 0);
        ISSUE_A(t + 1, 1);
        BARX(); LGKM0();
        MMA(0, 0);
        GATE(6);                          // A1(t), B1(t) landed
        BARX();
        // phase j1 (ah0, bh1)
        READ_B(b, 1);
        ISSUE_B(t + 1, 1);
        BARX(); LGKM0();
        MMA(0, 1);
        GATE(10);                         // (vacuous in steady state)
        BARX();
        // phase j2 (ah1, bh0)
        READ_A(b, 1);
        if (!last) ISSUE_A(t + 2, 0);
        BARX(); LGKM0();
        MMA(1, 0);
        BARX();
        // phase j3 (ah1, bh1)
        if (!last) ISSUE_B(t + 2, 0);
        MMA(1, 1);
        if (last) { GATE(4); } else { GATE(8); }   // A0,B0(t+1) landed
        BARX();
    }

    // ---- tail tile NT-1 (no issues) ----
    {
        const int b = (NT - 1) & 1;
        READ_A(b, 0);
        READ_B(b, 0);
        BARX(); LGKM0();
        MMA(0, 0);
        GATE(0);                          // A1,B1(NT-1) landed
        BARX();
        READ_B(b, 1);
        BARX(); LGKM0();
        MMA(0, 1);
        BARX();
        READ_A(b, 1);
        BARX(); LGKM0();
        MMA(1, 0);
        MMA(1, 1);
    }
    #undef ISSUE_A
    #undef ISSUE_B
    #undef READ_A
    #undef READ_B
    #undef MMA

    // ---- epilogue: per-row top2 over this block's 256 codes (u32 keys) ----
    #pragma unroll
    for (int ah = 0; ah < 2; ++ah)
        #pragma unroll
        for (int m = 0; m < 4; ++m) {
            u32 k1[4], k2[4];
            #pragma unroll
            for (int r = 0; r < 4; ++r) { k1[r] = ~0u; k2[r] = ~0u; }
            #pragma unroll
            for (int bh = 0; bh < 2; ++bh)
                #pragma unroll
                for (int n = 0; n < 2; ++n) {
                    const int code = code0 + bh * 128 + wc * 32 + n * 16 + c;
                    const float cc = c2f[code];
                    const u32 bin = (u32)(code & 1023);
                    #pragma unroll
                    for (int r = 0; r < 4; ++r) {
                        const float sc = cc - 2.0f * acc[ah][bh][m][n][r];
                        const u32 key = (mapf(sc) & 0xFFFFFC00u) | bin;
                        if (key < k1[r]) { k2[r] = k1[r]; k1[r] = key; }
                        else if (key < k2[r]) k2[r] = key;
                    }
                }
            #pragma unroll
            for (int r = 0; r < 4; ++r) {
                #pragma unroll
                for (int mask = 1; mask <= 8; mask <<= 1) {
                    const u32 o1 = __shfl_xor(k1[r], mask, 64);
                    const u32 o2 = __shfl_xor(k2[r], mask, 64);
                    const u32 hi = k1[r] > o1 ? k1[r] : o1;
                    k1[r] = k1[r] < o1 ? k1[r] : o1;
                    const u32 lo2 = o2 < k2[r] ? o2 : k2[r];
                    k2[r] = hi < lo2 ? hi : lo2;
                }
            }
            if (c == 0) {
                #pragma unroll
                for (int r = 0; r < 4; ++r) {
                    const int rowt = ah * 128 + wr * 64 + m * 16 + g * 4 + r;
                    red[rowt][wc * 2]     = k1[r];
                    red[rowt][wc * 2 + 1] = k2[r];
                }
            }
        }
    __syncthreads();

    if (tid < 256) {
        u32 b1 = ~0u, b2 = ~0u;
        #pragma unroll
        for (int jj = 0; jj < 8; ++jj) {
            const u32 k = red[tid][jj];
            if (k < b1) { b2 = b1; b1 = k; }
            else if (k < b2) b2 = k;
        }
        cand[(size_t)ct * NROWS + n0 + tid] = ((u64)b2 << 32) | (u64)b1;
    }
}

// ---------------- refine: merge 8 cands -> top4 -> exact fp64 rescore ----
// grid = 16384 rows; wave w handles q = {2w, 2w+1}
__global__ __launch_bounds__(256)
void refine_kernel(const u64* __restrict__ cand, const float* __restrict__ x_t,
                   const float* __restrict__ cb, const double* __restrict__ c2d,
                   float* __restrict__ idx_f, int* __restrict__ idx_i) {
    const int tid  = threadIdx.x;
    const int lane = tid & 63;
    const int w    = tid >> 6;
    const int row  = blockIdx.x;
    const float4 x4 = *(const float4*)(x_t + (size_t)row * C_ + lane * 4);
    #pragma unroll
    for (int t = 0; t < 2; ++t) {
        const int q = w * 2 + t;
        u64 pack = ~0ull;
        if (lane < 4)
            pack = cand[((size_t)(q * 4 + lane) * NROWS) + row];
        // all lanes build the top-4 of the 8 candidate u32 keys
        u32 s0 = ~0u, s1 = ~0u, s2 = ~0u, s3 = ~0u;
        #pragma unroll
        for (int i = 0; i < 4; ++i) {
            const u64 p = __shfl(pack, i, 64);
            #pragma unroll
            for (int hlf = 0; hlf < 2; ++hlf) {
                const u32 k = (u32)(p >> (hlf * 32));
                if (k < s0)      { s3 = s2; s2 = s1; s1 = s0; s0 = k; }
                else if (k < s1) { s3 = s2; s2 = s1; s1 = k; }
                else if (k < s2) { s3 = s2; s2 = k; }
                else if (k < s3) { s3 = k; }
            }
        }
        const int bins[4] = {(int)(s0 & 1023u), (int)(s1 & 1023u),
                             (int)(s2 & 1023u), (int)(s3 & 1023u)};
        double d[4];
        #pragma unroll
        for (int i = 0; i < 4; ++i) {
            const float4 cv =
                *(const float4*)(cb + ((size_t)(q * BINS + bins[i]) * C_) + lane * 4);
            d[i] = (double)x4.x * cv.x + (double)x4.y * cv.y +
                   (double)x4.z * cv.z + (double)x4.w * cv.w;
        }
        #pragma unroll
        for (int off = 32; off; off >>= 1)
            #pragma unroll
            for (int i = 0; i < 4; ++i) d[i] += __shfl_down(d[i], off, 64);
        if (lane == 0) {
            double best = 1e300;
            int win = BINS;
            #pragma unroll
            for (int i = 0; i < 4; ++i) {
                const double s = c2d[q * BINS + bins[i]] - 2.0 * d[i];
                if (s < best || (s == best && bins[i] < win)) {
                    best = s; win = bins[i];
                }
            }
            idx_f[(size_t)row * NQ + q] = (float)win;
            idx_i[(size_t)row * NQ + q] = win;
        }
    }
}

// ---------------- gather: q_ste output + loss ----------------------------
__global__ __launch_bounds__(256)
void gather_kernel(const float* __restrict__ x, const float* __restrict__ cb,
                   const int* __restrict__ idx_i, float* __restrict__ out,
                   float* __restrict__ loss) {
    __shared__ float ql[C_][17];
    const int blk = blockIdx.x;
    const int b   = blk >> 7;
    const int t0  = (blk & 127) << 4;
    const int tid = threadIdx.x;
    {
        const int c = tid;
        for (int nl = 0; nl < 16; ++nl) {
            const int n = b * T_ + t0 + nl;
            float acc = 0.f;
            #pragma unroll
            for (int qq = 0; qq < NQ; ++qq) {
                const int id = idx_i[(size_t)n * NQ + qq];
                acc += cb[((size_t)qq * BINS + id) * C_ + c];
            }
            ql[c][nl] = acc;
        }
    }
    __syncthreads();
    const int tx = tid & 15, ty = tid >> 4;
    float lsum = 0.f;
    for (int cg = 0; cg < 16; ++cg) {
        const int c = cg * 16 + ty;
        const size_t off = ((size_t)b * C_ + c) * T_ + t0 + tx;
        const float qv = ql[c][tx];
        const float xv = x[off];
        out[off] = qv;
        const float d = qv - xv;
        lsum += d * d;
    }
    #pragma unroll
    for (int off = 32; off; off >>= 1) lsum += __shfl_down(lsum, off, 64);
    if ((tid & 63) == 0)
        atomicAdd(loss, lsum * (2.0f / (float)(B_ * C_ * T_)));
}

extern "C" void kernel_launch(void* const* d_in, const int* in_sizes, int n_in,
                              void* d_out, int out_size, void* d_ws, size_t ws_size,
                              hipStream_t stream) {
    const float* x  = (const float*)d_in[0];
    const float* cb = (const float*)d_in[1];

    float* out   = (float*)d_out;
    float* idx_f = out + (size_t)B_ * C_ * T_;
    float* loss  = idx_f + (size_t)NROWS * NQ;

    char* ws = (char*)d_ws;
    f16*    xs    = (f16*)(ws + XS_OFF);
    f16*    cs    = (f16*)(ws + CS_OFF);
    float*  x_t   = (float*)(ws + XT_OFF);
    u64*    cand  = (u64*)(ws + CAND_OFF);
    double* c2d   = (double*)(ws + C2D_OFF);
    float*  c2f   = (float*)(ws + C2F_OFF);
    int*    idx_i = (int*)(ws + IDXI_OFF);

    hipMemsetAsync(loss, 0, sizeof(float), stream);
    prep_x<<<1024, 256, 0, stream>>>(x, x_t, xs);
    prep_cb_c2<<<2048, 256, 0, stream>>>(cb, cs, c2d, c2f);
    dist_kernel<<<2048, 512, 0, stream>>>(xs, cs, c2f, cand);
    refine_kernel<<<NROWS, 256, 0, stream>>>(cand, x_t, cb, c2d, idx_f, idx_i);
    gather_kernel<<<B_ * (T_ / 16), 256, 0, stream>>>(x, cb, idx_i, out, loss);
}

// Round 8
// 272.092 us; speedup vs baseline: 4.6969x; 1.0616x over previous
//
#include <hip/hip_runtime.h>

typedef unsigned long long u64;
typedef unsigned int u32;
typedef _Float16 f16;
typedef f16 f16x8 __attribute__((ext_vector_type(8)));
typedef float f32x4 __attribute__((ext_vector_type(4)));

#define B_   8
#define C_   256
#define T_   2048
#define NQ   8
#define BINS 1024
#define NROWS (B_ * T_)          // 16384
#define KA   256                 // A: single fp16 limb (row-major [n][256])
#define KB   256                 // B: single fp16 limb (row-major [code][256])
#define NTILE 16                 // 1024 codes / 64 per tile

// ---- workspace layout (bytes) ----
#define XS_OFF   ((size_t)0)                       // f16 [16384][256]   =  8388608
#define CS_OFF   ((size_t)8388608)                 // f16 [8192][256]    =  4194304
#define XT_OFF   ((size_t)12582912)                // f32 [16384][256]   = 16777216
#define CAND_OFF ((size_t)29360128)                // u64 [8][16384][2]  =  2097152
#define C2D_OFF  ((size_t)33554432)                // f64 [8192]         =    65536
#define C2F_OFF  ((size_t)33619968)                // f32 [8192]         =    32768
#define IDXI_OFF ((size_t)33652736)                // i32 [131072]       =   524288

static __device__ __forceinline__ void gll16(const void* g, void* l) {
    __builtin_amdgcn_global_load_lds(
        (const __attribute__((address_space(1))) u32*)g,
        (__attribute__((address_space(3))) u32*)l, 16, 0, 0);
}

static __device__ __forceinline__ u32 mapf(float f) {
    u32 u = __float_as_uint(f);
    return (u & 0x80000000u) ? ~u : (u | 0x80000000u);
}

// ---------------- prep_x: transpose + fp16 cast --------------------------
__global__ __launch_bounds__(256)
void prep_x(const float* __restrict__ x, float* __restrict__ x_t,
            f16* __restrict__ xs) {
    __shared__ float tile[64][65];
    const int tid = threadIdx.x;
    const int bid = blockIdx.x;
    const int b  = bid >> 7;
    const int c0 = ((bid >> 5) & 3) * 64;
    const int t0 = (bid & 31) * 64;
    {
        const int j = tid & 63, cg = tid >> 6;
        #pragma unroll
        for (int ii = 0; ii < 16; ++ii) {
            const int cl = cg * 16 + ii;
            tile[cl][j] = x[((size_t)(b * C_ + c0 + cl) * T_) + t0 + j];
        }
    }
    __syncthreads();
    {
        const int cl = tid & 63, tg = tid >> 6;
        #pragma unroll
        for (int jj = 0; jj < 16; ++jj) {
            const int tl = tg * 16 + jj;
            const float v = tile[cl][tl];
            const size_t n = (size_t)b * T_ + t0 + tl;
            x_t[n * C_ + c0 + cl] = v;
            xs[n * KA + c0 + cl]  = (f16)v;
        }
    }
}

// ---------------- prep_cb_c2: fp16 codebook + exact norms ----------------
struct alignas(8) H4 { f16 v[4]; };
__global__ __launch_bounds__(256)
void prep_cb_c2(const float* __restrict__ cb, f16* __restrict__ cs,
                double* __restrict__ c2d, float* __restrict__ c2f) {
    const int w    = threadIdx.x >> 6;
    const int lane = threadIdx.x & 63;
    const int code = blockIdx.x * 4 + w;
    const float4 v = *(const float4*)(cb + (size_t)code * C_ + lane * 4);
    H4 h;
    h.v[0] = (f16)v.x; h.v[1] = (f16)v.y; h.v[2] = (f16)v.z; h.v[3] = (f16)v.w;
    *(H4*)(cs + (size_t)code * KB + lane * 4) = h;
    double s = (double)v.x * v.x + (double)v.y * v.y +
               (double)v.z * v.z + (double)v.w * v.w;
    #pragma unroll
    for (int off = 32; off; off >>= 1) s += __shfl_down(s, off, 64);
    if (lane == 0) { c2d[code] = s; c2f[code] = (float)s; }
}

// ---------------- dist v3: register-A, streamed-B, per-q top4 ------------
// grid = 128 rt x 8 q = 1024 blocks (bid = rt*8 + q -> XCD k serves q=k),
// 1024 threads = 16 waves (4 wr x 4 wc). Each wave: 32 rows x K=256 of A in
// registers (af[2][8]); B tiles of 64 codes stream through LDS dbuf with
// one __syncthreads per tile (T3-minimal). Wave covers all 1024 codes of q
// for its rows (16 codes/tile via wc) -> per-row top2 complete in-wave.
// LDS swizzle: P[c][sp] = L[c][sp ^ (c&7)] (16B slots), via pre-swizzled
// global source (rule #21); frag reads 2 lanes/bank = conflict-free.
__global__ __launch_bounds__(1024)
void dist_kernel(const f16* __restrict__ xs, const f16* __restrict__ cs,
                 const float* __restrict__ c2f, u64* __restrict__ cand) {
    __shared__ f16 Bs[2][64][256];       // 64 KB
    __shared__ u32 red[128][8];          // 4 KB

    const int tid  = threadIdx.x;
    const int lane = tid & 63;
    const int w    = tid >> 6;           // 0..15
    const int wr   = w >> 2;             // 0..3 row group (32 rows each)
    const int wc   = w & 3;              // 0..3 code column (16 codes/tile)
    const int bid  = blockIdx.x;
    const int q    = bid & 7;
    const int rt   = bid >> 3;
    const int n0   = rt * 128;

    const int c = lane & 15;             // MFMA col / frag row
    const int g = lane >> 4;             // 0..3 k-group

    // ---- A fragments in registers: rows n0 + wr*32 + m*16 + c ----
    f16x8 af[2][8];
    {
        const f16* pa = xs + (size_t)(n0 + wr * 32 + c) * KA + g * 8;
        #pragma unroll
        for (int m = 0; m < 2; ++m)
            #pragma unroll
            for (int kk = 0; kk < 8; ++kk)
                af[m][kk] = *(const f16x8*)(pa + m * 16 * KA + kk * 32);
    }

    // ---- staging: 2 x gll16 per thread per tile ----
    const int crow  = tid >> 5;                    // 0..31 (i=0), +32 (i=1)
    const int slotl = (tid & 31) ^ (crow & 7);     // inverse-swizzled source
    const f16* pb = cs + (size_t)q * 1024 * KB;
    const int wbase = w * 512;                     // uniform dest (f16)

    #define STAGE(buf, t)                                                    \
        do {                                                                 \
            f16* b0 = &Bs[buf][0][0];                                        \
            const f16* s_ = pb + (size_t)((t) * 64 + crow) * KB + slotl * 8; \
            gll16(s_,            b0 + wbase);                                \
            gll16(s_ + 32 * KB,  b0 + 8192 + wbase);                         \
        } while (0)

    // per-(thread,row) top-2 keys: rows (m, r)
    u32 k1[2][4], k2[2][4];
    #pragma unroll
    for (int m = 0; m < 2; ++m)
        #pragma unroll
        for (int r = 0; r < 4; ++r) { k1[m][r] = ~0u; k2[m][r] = ~0u; }

    const float* c2q = c2f + q * BINS;
    const int rowoff = (wc * 16 + c) * 256;        // B frag row base (f16)
    const int sw = c & 7;

    STAGE(0, 0);
    __syncthreads();

    #pragma unroll 1
    for (int t = 0; t < NTILE; ++t) {
        const int buf = t & 1;
        if (t < NTILE - 1) STAGE(buf ^ 1, t + 1);

        f32x4 acc[2];
        #pragma unroll
        for (int m = 0; m < 2; ++m) {
            f32x4 z = {0.f, 0.f, 0.f, 0.f};
            acc[m] = z;
        }

        const f16* bb = &Bs[buf][0][0] + rowoff;
        #pragma unroll
        for (int half = 0; half < 2; ++half) {
            f16x8 bg[4];
            #pragma unroll
            for (int k4 = 0; k4 < 4; ++k4) {
                const int kk = half * 4 + k4;
                bg[k4] = *(const f16x8*)(bb + ((kk * 4 + g) ^ sw) * 8);
            }
            #pragma unroll
            for (int k4 = 0; k4 < 4; ++k4)
                #pragma unroll
                for (int m = 0; m < 2; ++m)
                    acc[m] = __builtin_amdgcn_mfma_f32_16x16x32_f16(
                        af[m][half * 4 + k4], bg[k4], acc[m], 0, 0, 0);
        }

        // top-2 insert for this tile's 8 acc values
        const int codeL = t * 64 + wc * 16 + c;
        const float cc = c2q[codeL];
        #pragma unroll
        for (int m = 0; m < 2; ++m)
            #pragma unroll
            for (int r = 0; r < 4; ++r) {
                const float sc = fmaf(-2.f, acc[m][r], cc);
                const u32 key = (mapf(sc) & 0xFFFFFC00u) | (u32)codeL;
                if (key < k1[m][r]) { k2[m][r] = k1[m][r]; k1[m][r] = key; }
                else if (key < k2[m][r]) k2[m][r] = key;
            }

        __syncthreads();   // drains prefetch (vmcnt0) + publishes buf^1
    }
    #undef STAGE

    // ---- merge: 16 lanes (codes) per row -> wave top2 -> red ----
    #pragma unroll
    for (int m = 0; m < 2; ++m)
        #pragma unroll
        for (int r = 0; r < 4; ++r) {
            u32 a1 = k1[m][r], a2 = k2[m][r];
            #pragma unroll
            for (int mask = 1; mask <= 8; mask <<= 1) {
                const u32 o1 = __shfl_xor(a1, mask, 64);
                const u32 o2 = __shfl_xor(a2, mask, 64);
                const u32 hi = a1 > o1 ? a1 : o1;
                a1 = a1 < o1 ? a1 : o1;
                const u32 lo2 = o2 < a2 ? o2 : a2;
                a2 = hi < lo2 ? hi : lo2;
            }
            if (c == 0) {
                const int rowl = wr * 32 + m * 16 + g * 4 + r;
                red[rowl][wc * 2]     = a1;
                red[rowl][wc * 2 + 1] = a2;
            }
        }
    __syncthreads();

    if (tid < 128) {
        u32 s0 = ~0u, s1 = ~0u, s2 = ~0u, s3 = ~0u;
        #pragma unroll
        for (int jj = 0; jj < 8; ++jj) {
            const u32 k = red[tid][jj];
            if (k < s0)      { s3 = s2; s2 = s1; s1 = s0; s0 = k; }
            else if (k < s1) { s3 = s2; s2 = s1; s1 = k; }
            else if (k < s2) { s3 = s2; s2 = k; }
            else if (k < s3) { s3 = k; }
        }
        u64* dst = cand + ((size_t)q * NROWS + n0 + tid) * 2;
        dst[0] = ((u64)s1 << 32) | (u64)s0;
        dst[1] = ((u64)s3 << 32) | (u64)s2;
    }
}

// ---------------- refine: exact fp64 rescore of per-q top4 ---------------
// grid = 16384 rows; wave w handles q = {2w, 2w+1}
__global__ __launch_bounds__(256)
void refine_kernel(const u64* __restrict__ cand, const float* __restrict__ x_t,
                   const float* __restrict__ cb, const double* __restrict__ c2d,
                   float* __restrict__ idx_f, int* __restrict__ idx_i) {
    const int tid  = threadIdx.x;
    const int lane = tid & 63;
    const int w    = tid >> 6;
    const int row  = blockIdx.x;
    const float4 x4 = *(const float4*)(x_t + (size_t)row * C_ + lane * 4);
    #pragma unroll
    for (int t = 0; t < 2; ++t) {
        const int q = w * 2 + t;
        const u64* cp = cand + ((size_t)q * NROWS + row) * 2;
        const u64 p0 = cp[0], p1 = cp[1];
        const int bins[4] = {(int)(p0 & 1023ull), (int)((p0 >> 32) & 1023ull),
                             (int)(p1 & 1023ull), (int)((p1 >> 32) & 1023ull)};
        double d[4];
        #pragma unroll
        for (int i = 0; i < 4; ++i) {
            const float4 cv =
                *(const float4*)(cb + ((size_t)(q * BINS + bins[i]) * C_) + lane * 4);
            d[i] = (double)x4.x * cv.x + (double)x4.y * cv.y +
                   (double)x4.z * cv.z + (double)x4.w * cv.w;
        }
        #pragma unroll
        for (int off = 32; off; off >>= 1)
            #pragma unroll
            for (int i = 0; i < 4; ++i) d[i] += __shfl_down(d[i], off, 64);
        if (lane == 0) {
            double best = 1e300;
            int win = BINS;
            #pragma unroll
            for (int i = 0; i < 4; ++i) {
                const double s = c2d[q * BINS + bins[i]] - 2.0 * d[i];
                if (s < best || (s == best && bins[i] < win)) {
                    best = s; win = bins[i];
                }
            }
            idx_f[(size_t)row * NQ + q] = (float)win;
            idx_i[(size_t)row * NQ + q] = win;
        }
    }
}

// ---------------- gather: q_ste output + loss ----------------------------
__global__ __launch_bounds__(256)
void gather_kernel(const float* __restrict__ x, const float* __restrict__ cb,
                   const int* __restrict__ idx_i, float* __restrict__ out,
                   float* __restrict__ loss) {
    __shared__ float ql[C_][17];
    const int blk = blockIdx.x;
    const int b   = blk >> 7;
    const int t0  = (blk & 127) << 4;
    const int tid = threadIdx.x;
    {
        const int c = tid;
        for (int nl = 0; nl < 16; ++nl) {
            const int n = b * T_ + t0 + nl;
            float acc = 0.f;
            #pragma unroll
            for (int qq = 0; qq < NQ; ++qq) {
                const int id = idx_i[(size_t)n * NQ + qq];
                acc += cb[((size_t)qq * BINS + id) * C_ + c];
            }
            ql[c][nl] = acc;
        }
    }
    __syncthreads();
    const int tx = tid & 15, ty = tid >> 4;
    float lsum = 0.f;
    for (int cg = 0; cg < 16; ++cg) {
        const int c = cg * 16 + ty;
        const size_t off = ((size_t)b * C_ + c) * T_ + t0 + tx;
        const float qv = ql[c][tx];
        const float xv = x[off];
        out[off] = qv;
        const float d = qv - xv;
        lsum += d * d;
    }
    #pragma unroll
    for (int off = 32; off; off >>= 1) lsum += __shfl_down(lsum, off, 64);
    if ((tid & 63) == 0)
        atomicAdd(loss, lsum * (2.0f / (float)(B_ * C_ * T_)));
}

extern "C" void kernel_launch(void* const* d_in, const int* in_sizes, int n_in,
                              void* d_out, int out_size, void* d_ws, size_t ws_size,
                              hipStream_t stream) {
    const float* x  = (const float*)d_in[0];
    const float* cb = (const float*)d_in[1];

    float* out   = (float*)d_out;
    float* idx_f = out + (size_t)B_ * C_ * T_;
    float* loss  = idx_f + (size_t)NROWS * NQ;

    char* ws = (char*)d_ws;
    f16*    xs    = (f16*)(ws + XS_OFF);
    f16*    cs    = (f16*)(ws + CS_OFF);
    float*  x_t   = (float*)(ws + XT_OFF);
    u64*    cand  = (u64*)(ws + CAND_OFF);
    double* c2d   = (double*)(ws + C2D_OFF);
    float*  c2f   = (float*)(ws + C2F_OFF);
    int*    idx_i = (int*)(ws + IDXI_OFF);

    hipMemsetAsync(loss, 0, sizeof(float), stream);
    prep_x<<<1024, 256, 0, stream>>>(x, x_t, xs);
    prep_cb_c2<<<2048, 256, 0, stream>>>(cb, cs, c2d, c2f);
    dist_kernel<<<1024, 1024, 0, stream>>>(xs, cs, c2f, cand);
    refine_kernel<<<NROWS, 256, 0, stream>>>(cand, x_t, cb, c2d, idx_f, idx_i);
    gather_kernel<<<B_ * (T_ / 16), 256, 0, stream>>>(x, cb, idx_i, out, loss);
}

// Round 10
// 261.488 us; speedup vs baseline: 4.8874x; 1.0406x over previous
//
#include <hip/hip_runtime.h>

typedef unsigned long long u64;
typedef unsigned int u32;
typedef _Float16 f16;
typedef f16 f16x8 __attribute__((ext_vector_type(8)));
typedef float f32x4 __attribute__((ext_vector_type(4)));

#define B_   8
#define C_   256
#define T_   2048
#define NQ   8
#define BINS 1024
#define NROWS (B_ * T_)          // 16384
#define KA   256                 // A: single fp16 limb (row-major [n][256])
#define KB   256                 // B: single fp16 limb (row-major [code][256])
#define NTILE 16                 // 1024 codes / 64 per tile

// ---- workspace layout (bytes) ----
#define XS_OFF   ((size_t)0)                       // f16 [16384][256]   =  8388608
#define CS_OFF   ((size_t)8388608)                 // f16 [8192][256]    =  4194304
#define XT_OFF   ((size_t)12582912)                // f32 [16384][256]   = 16777216
#define C2D_OFF  ((size_t)29360128)                // f64 [8192]         =    65536
#define C2K_OFF  ((size_t)29425664)                // f32 [8192] biased  =    32768
#define IDXI_OFF ((size_t)29458432)                // i32 [131072]       =   524288

static __device__ __forceinline__ void gll16(const void* g, void* l) {
    __builtin_amdgcn_global_load_lds(
        (const __attribute__((address_space(1))) u32*)g,
        (__attribute__((address_space(3))) u32*)l, 16, 0, 0);
}

// ---------------- prep_x: transpose + fp16 cast --------------------------
__global__ __launch_bounds__(256)
void prep_x(const float* __restrict__ x, float* __restrict__ x_t,
            f16* __restrict__ xs) {
    __shared__ float tile[64][65];
    const int tid = threadIdx.x;
    const int bid = blockIdx.x;
    const int b  = bid >> 7;
    const int c0 = ((bid >> 5) & 3) * 64;
    const int t0 = (bid & 31) * 64;
    {
        const int j = tid & 63, cg = tid >> 6;
        #pragma unroll
        for (int ii = 0; ii < 16; ++ii) {
            const int cl = cg * 16 + ii;
            tile[cl][j] = x[((size_t)(b * C_ + c0 + cl) * T_) + t0 + j];
        }
    }
    __syncthreads();
    {
        const int cl = tid & 63, tg = tid >> 6;
        #pragma unroll
        for (int jj = 0; jj < 16; ++jj) {
            const int tl = tg * 16 + jj;
            const float v = tile[cl][tl];
            const size_t n = (size_t)b * T_ + t0 + tl;
            x_t[n * C_ + c0 + cl] = v;
            xs[n * KA + c0 + cl]  = (f16)v;
        }
    }
}

// ---------------- prep_cb_c2: fp16 codebook + norms (exact & biased) -----
struct alignas(8) H4 { f16 v[4]; };
__global__ __launch_bounds__(256)
void prep_cb_c2(const float* __restrict__ cb, f16* __restrict__ cs,
                double* __restrict__ c2d, float* __restrict__ c2k) {
    const int w    = threadIdx.x >> 6;
    const int lane = threadIdx.x & 63;
    const int code = blockIdx.x * 4 + w;
    const float4 v = *(const float4*)(cb + (size_t)code * C_ + lane * 4);
    H4 h;
    h.v[0] = (f16)v.x; h.v[1] = (f16)v.y; h.v[2] = (f16)v.z; h.v[3] = (f16)v.w;
    *(H4*)(cs + (size_t)code * KB + lane * 4) = h;
    double s = (double)v.x * v.x + (double)v.y * v.y +
               (double)v.z * v.z + (double)v.w * v.w;
    #pragma unroll
    for (int off = 32; off; off >>= 1) s += __shfl_down(s, off, 64);
    if (lane == 0) {
        c2d[code] = s;                        // exact norm (fp64 rescore)
        c2k[code] = (float)s + 1000.0f;       // biased: sc = c2+1000-2xc > 0
    }
}

// ---------------- dist v4b: register-A, streamed-B, fused exact rescore --
// grid = 128 rt x 8 q = 1024 blocks (bid&7 = q -> XCD-local codebook),
// 1024 threads = 16 waves (4 wr x 4 wc). A (32 rows x K=256) in registers;
// B streams thru 64-code LDS dbuf, 1 barrier/tile. Scores use positive-
// biased float-bit keys (monotone u32) -> 6 VALU/score. Per-row top-4 is
// exact-rescored in fp64 in-kernel (refine fused).
// r9 bugfix: candidate-dist broadcast shfls hoisted to FULL-WAVE uniform
// code — ds_bpermute from an exec-masked-off lane returns 0, so the old
// divergent if/else read dist=0 for candidates 1..3 and picked wrong bins.
__global__ __launch_bounds__(1024)
void dist_kernel(const f16* __restrict__ xs, const f16* __restrict__ cs,
                 const float* __restrict__ c2k, const float* __restrict__ x_t,
                 const float* __restrict__ cb, const double* __restrict__ c2d,
                 float* __restrict__ idx_f, int* __restrict__ idx_i) {
    __shared__ f16 Bs[2][64][256];       // 64 KB
    __shared__ u32 red[128][8];          // 4 KB

    const int tid  = threadIdx.x;
    const int lane = tid & 63;
    const int w    = tid >> 6;           // 0..15
    const int wr   = w >> 2;             // 0..3 row group (32 rows each)
    const int wc   = w & 3;              // 0..3 code column (16 codes/tile)
    const int bid  = blockIdx.x;
    const int q    = bid & 7;
    const int rt   = bid >> 3;
    const int n0   = rt * 128;

    const int c = lane & 15;             // MFMA col / frag row
    const int g = lane >> 4;             // 0..3 k-group

    // ---- A fragments in registers: rows n0 + wr*32 + m*16 + c ----
    f16x8 af[2][8];
    {
        const f16* pa = xs + (size_t)(n0 + wr * 32 + c) * KA + g * 8;
        #pragma unroll
        for (int m = 0; m < 2; ++m)
            #pragma unroll
            for (int kk = 0; kk < 8; ++kk)
                af[m][kk] = *(const f16x8*)(pa + m * 16 * KA + kk * 32);
    }

    // ---- staging: 2 x gll16 per thread per tile ----
    const int crow  = tid >> 5;                    // 0..31 (i=0), +32 (i=1)
    const int slotl = (tid & 31) ^ (crow & 7);     // inverse-swizzled source
    const f16* pb = cs + (size_t)q * 1024 * KB;
    const int wbase = w * 512;                     // uniform dest (f16)

    #define STAGE(buf, t)                                                    \
        do {                                                                 \
            f16* b0 = &Bs[buf][0][0];                                        \
            const f16* s_ = pb + (size_t)((t) * 64 + crow) * KB + slotl * 8; \
            gll16(s_,            b0 + wbase);                                \
            gll16(s_ + 32 * KB,  b0 + 8192 + wbase);                         \
        } while (0)

    // per-(thread,row) top-2 keys: rows (m, r)
    u32 k1[2][4], k2[2][4];
    #pragma unroll
    for (int m = 0; m < 2; ++m)
        #pragma unroll
        for (int r = 0; r < 4; ++r) { k1[m][r] = ~0u; k2[m][r] = ~0u; }

    const float* c2q = c2k + q * BINS;
    const int rowoff = (wc * 16 + c) * 256;        // B frag row base (f16)
    const int sw = c & 7;

    STAGE(0, 0);
    __syncthreads();

    #pragma unroll 1
    for (int t = 0; t < NTILE; ++t) {
        const int buf = t & 1;
        if (t < NTILE - 1) STAGE(buf ^ 1, t + 1);

        f32x4 acc[2];
        #pragma unroll
        for (int m = 0; m < 2; ++m) {
            f32x4 z = {0.f, 0.f, 0.f, 0.f};
            acc[m] = z;
        }

        const f16* bb = &Bs[buf][0][0] + rowoff;
        #pragma unroll
        for (int half = 0; half < 2; ++half) {
            f16x8 bg[4];
            #pragma unroll
            for (int k4 = 0; k4 < 4; ++k4) {
                const int kk = half * 4 + k4;
                bg[k4] = *(const f16x8*)(bb + ((kk * 4 + g) ^ sw) * 8);
            }
            #pragma unroll
            for (int k4 = 0; k4 < 4; ++k4)
                #pragma unroll
                for (int m = 0; m < 2; ++m)
                    acc[m] = __builtin_amdgcn_mfma_f32_16x16x32_f16(
                        af[m][half * 4 + k4], bg[k4], acc[m], 0, 0, 0);
        }

        // top-2 insert (6 VALU/score): positive floats -> bits monotone
        const int codeL = t * 64 + wc * 16 + c;
        const float cc = c2q[codeL];
        #pragma unroll
        for (int m = 0; m < 2; ++m)
            #pragma unroll
            for (int r = 0; r < 4; ++r) {
                const float sc = fmaf(-2.f, acc[m][r], cc);
                const u32 key = (__float_as_uint(sc) & 0xFFFFFC00u) | (u32)codeL;
                const u32 hi = k1[m][r] > key ? k1[m][r] : key;
                k1[m][r] = k1[m][r] < key ? k1[m][r] : key;
                k2[m][r] = k2[m][r] < hi ? k2[m][r] : hi;
            }

        __syncthreads();   // drains prefetch (vmcnt0) + publishes buf^1
    }
    #undef STAGE

    // ---- merge: 16 lanes (codes) per row -> wave top2 -> red ----
    #pragma unroll
    for (int m = 0; m < 2; ++m)
        #pragma unroll
        for (int r = 0; r < 4; ++r) {
            u32 a1 = k1[m][r], a2 = k2[m][r];
            #pragma unroll
            for (int mask = 1; mask <= 8; mask <<= 1) {
                const u32 o1 = __shfl_xor(a1, mask, 64);
                const u32 o2 = __shfl_xor(a2, mask, 64);
                const u32 hi = a1 > o1 ? a1 : o1;
                a1 = a1 < o1 ? a1 : o1;
                const u32 lo2 = o2 < a2 ? o2 : a2;
                a2 = hi < lo2 ? hi : lo2;
            }
            if (c == 0) {
                const int rowl = wr * 32 + m * 16 + g * 4 + r;
                red[rowl][wc * 2]     = a1;
                red[rowl][wc * 2 + 1] = a2;
            }
        }
    __syncthreads();

    // ---- per-row top-4 of the 8 wave-candidates -> bins into red[..][0..3]
    if (tid < 128) {
        u32 s0 = ~0u, s1 = ~0u, s2 = ~0u, s3 = ~0u;
        #pragma unroll
        for (int jj = 0; jj < 8; ++jj) {
            const u32 k = red[tid][jj];
            if (k < s0)      { s3 = s2; s2 = s1; s1 = s0; s0 = k; }
            else if (k < s1) { s3 = s2; s2 = s1; s1 = k; }
            else if (k < s2) { s3 = s2; s2 = k; }
            else if (k < s3) { s3 = k; }
        }
        red[tid][0] = s0 & 1023u;
        red[tid][1] = s1 & 1023u;
        red[tid][2] = s2 & 1023u;
        red[tid][3] = s3 & 1023u;
    }
    __syncthreads();

    // ---- fused exact rescore (fp64): wave w handles rows w*8..w*8+7 ----
    {
        const int cand = lane >> 4;      // 0..3
        const int cg   = lane & 15;      // 16-float chunk of C_
        #pragma unroll 1
        for (int i = 0; i < 8; ++i) {
            const int rl = w * 8 + i;
            const int n  = n0 + rl;
            const int bin = (int)red[rl][cand];
            const float* xr = x_t + (size_t)n * C_ + cg * 16;
            const float* cr = cb + ((size_t)(q * BINS + bin)) * C_ + cg * 16;
            double d = 0.0;
            #pragma unroll
            for (int u = 0; u < 4; ++u) {
                const float4 xv = *(const float4*)(xr + u * 4);
                const float4 cv = *(const float4*)(cr + u * 4);
                d += (double)xv.x * cv.x + (double)xv.y * cv.y
                   + (double)xv.z * cv.z + (double)xv.w * cv.w;
            }
            #pragma unroll
            for (int off = 8; off; off >>= 1) d += __shfl_down(d, off, 16);
            const double dist = c2d[q * BINS + bin] - 2.0 * d; // valid @ cand*16
            // FULL-WAVE uniform broadcasts (all 64 lanes active here):
            const double d0 = __shfl(dist,  0, 64);
            const double d1 = __shfl(dist, 16, 64);
            const double d2 = __shfl(dist, 32, 64);
            const double d3 = __shfl(dist, 48, 64);
            if (lane == 0) {
                const int b0 = (int)red[rl][0], b1 = (int)red[rl][1];
                const int b2 = (int)red[rl][2], b3 = (int)red[rl][3];
                double best = d0;
                int win = b0;
                if (d1 < best || (d1 == best && b1 < win)) { best = d1; win = b1; }
                if (d2 < best || (d2 == best && b2 < win)) { best = d2; win = b2; }
                if (d3 < best || (d3 == best && b3 < win)) { best = d3; win = b3; }
                idx_f[(size_t)n * NQ + q] = (float)win;
                idx_i[(size_t)n * NQ + q] = win;
            }
        }
    }
}

// ---------------- gather: q_ste output + loss ----------------------------
__global__ __launch_bounds__(256)
void gather_kernel(const float* __restrict__ x, const float* __restrict__ cb,
                   const int* __restrict__ idx_i, float* __restrict__ out,
                   float* __restrict__ loss) {
    __shared__ float ql[C_][17];
    const int blk = blockIdx.x;
    const int b   = blk >> 7;
    const int t0  = (blk & 127) << 4;
    const int tid = threadIdx.x;
    {
        const int c = tid;
        for (int nl = 0; nl < 16; ++nl) {
            const int n = b * T_ + t0 + nl;
            float acc = 0.f;
            #pragma unroll
            for (int qq = 0; qq < NQ; ++qq) {
                const int id = idx_i[(size_t)n * NQ + qq];
                acc += cb[((size_t)qq * BINS + id) * C_ + c];
            }
            ql[c][nl] = acc;
        }
    }
    __syncthreads();
    const int tx = tid & 15, ty = tid >> 4;
    float lsum = 0.f;
    for (int cg = 0; cg < 16; ++cg) {
        const int c = cg * 16 + ty;
        const size_t off = ((size_t)b * C_ + c) * T_ + t0 + tx;
        const float qv = ql[c][tx];
        const float xv = x[off];
        out[off] = qv;
        const float d = qv - xv;
        lsum += d * d;
    }
    #pragma unroll
    for (int off = 32; off; off >>= 1) lsum += __shfl_down(lsum, off, 64);
    if ((tid & 63) == 0)
        atomicAdd(loss, lsum * (2.0f / (float)(B_ * C_ * T_)));
}

extern "C" void kernel_launch(void* const* d_in, const int* in_sizes, int n_in,
                              void* d_out, int out_size, void* d_ws, size_t ws_size,
                              hipStream_t stream) {
    const float* x  = (const float*)d_in[0];
    const float* cb = (const float*)d_in[1];

    float* out   = (float*)d_out;
    float* idx_f = out + (size_t)B_ * C_ * T_;
    float* loss  = idx_f + (size_t)NROWS * NQ;

    char* ws = (char*)d_ws;
    f16*    xs    = (f16*)(ws + XS_OFF);
    f16*    cs    = (f16*)(ws + CS_OFF);
    float*  x_t   = (float*)(ws + XT_OFF);
    double* c2d   = (double*)(ws + C2D_OFF);
    float*  c2k   = (float*)(ws + C2K_OFF);
    int*    idx_i = (int*)(ws + IDXI_OFF);

    hipMemsetAsync(loss, 0, sizeof(float), stream);
    prep_x<<<1024, 256, 0, stream>>>(x, x_t, xs);
    prep_cb_c2<<<2048, 256, 0, stream>>>(cb, cs, c2d, c2k);
    dist_kernel<<<1024, 1024, 0, stream>>>(xs, cs, c2k, x_t, cb, c2d,
                                           idx_f, idx_i);
    gather_kernel<<<B_ * (T_ / 16), 256, 0, stream>>>(x, cb, idx_i, out, loss);
}

// Round 11
// 231.620 us; speedup vs baseline: 5.5176x; 1.1290x over previous
//
#include <hip/hip_runtime.h>

typedef unsigned long long u64;
typedef unsigned int u32;
typedef _Float16 f16;
typedef f16 f16x8 __attribute__((ext_vector_type(8)));
typedef float f32x4 __attribute__((ext_vector_type(4)));

#define B_   8
#define C_   256
#define T_   2048
#define NQ   8
#define BINS 1024
#define NROWS (B_ * T_)          // 16384
#define KA   256                 // A: single fp16 limb (row-major [n][256])
#define KB   256                 // B: single fp16 limb (row-major [code][256])
#define NTILE 16                 // 1024 codes / 64 per tile
#define MARGIN 3.0f              // >> worst-case approx error (~0.6) + chop

// ---- workspace layout (bytes) ----
#define XS_OFF   ((size_t)0)                       // f16 [16384][256]   =  8388608
#define CS_OFF   ((size_t)8388608)                 // f16 [8192][256]    =  4194304
#define XT_OFF   ((size_t)12582912)                // f32 [16384][256]   = 16777216
#define C2D_OFF  ((size_t)29360128)                // f64 [8192]         =    65536
#define C2K_OFF  ((size_t)29425664)                // f32 [8192] biased  =    32768
#define IDXI_OFF ((size_t)29458432)                // i32 [131072]       =   524288

static __device__ __forceinline__ void gll16(const void* g, void* l) {
    __builtin_amdgcn_global_load_lds(
        (const __attribute__((address_space(1))) u32*)g,
        (__attribute__((address_space(3))) u32*)l, 16, 0, 0);
}

// ---------------- prep_x: transpose + fp16 cast --------------------------
__global__ __launch_bounds__(256)
void prep_x(const float* __restrict__ x, float* __restrict__ x_t,
            f16* __restrict__ xs) {
    __shared__ float tile[64][65];
    const int tid = threadIdx.x;
    const int bid = blockIdx.x;
    const int b  = bid >> 7;
    const int c0 = ((bid >> 5) & 3) * 64;
    const int t0 = (bid & 31) * 64;
    {
        const int j = tid & 63, cg = tid >> 6;
        #pragma unroll
        for (int ii = 0; ii < 16; ++ii) {
            const int cl = cg * 16 + ii;
            tile[cl][j] = x[((size_t)(b * C_ + c0 + cl) * T_) + t0 + j];
        }
    }
    __syncthreads();
    {
        const int cl = tid & 63, tg = tid >> 6;
        #pragma unroll
        for (int jj = 0; jj < 16; ++jj) {
            const int tl = tg * 16 + jj;
            const float v = tile[cl][tl];
            const size_t n = (size_t)b * T_ + t0 + tl;
            x_t[n * C_ + c0 + cl] = v;
            xs[n * KA + c0 + cl]  = (f16)v;
        }
    }
}

// ---------------- prep_cb_c2: fp16 codebook + norms (exact & biased) -----
struct alignas(8) H4 { f16 v[4]; };
__global__ __launch_bounds__(256)
void prep_cb_c2(const float* __restrict__ cb, f16* __restrict__ cs,
                double* __restrict__ c2d, float* __restrict__ c2k) {
    const int w    = threadIdx.x >> 6;
    const int lane = threadIdx.x & 63;
    const int code = blockIdx.x * 4 + w;
    const float4 v = *(const float4*)(cb + (size_t)code * C_ + lane * 4);
    H4 h;
    h.v[0] = (f16)v.x; h.v[1] = (f16)v.y; h.v[2] = (f16)v.z; h.v[3] = (f16)v.w;
    *(H4*)(cs + (size_t)code * KB + lane * 4) = h;
    double s = (double)v.x * v.x + (double)v.y * v.y +
               (double)v.z * v.z + (double)v.w * v.w;
    #pragma unroll
    for (int off = 32; off; off >>= 1) s += __shfl_down(s, off, 64);
    if (lane == 0) {
        c2d[code] = s;                        // exact norm (fp64 rescore)
        c2k[code] = (float)s + 1000.0f;       // biased: sc = c2+1000-2xc > 0
    }
}

// ---------------- dist v5: 8-wave 64-row reg-A, margin-skip rescore ------
// grid = 128 rt x 8 q = 1024 blocks (bid&7 = q -> XCD-local codebook),
// 512 threads = 8 waves (2 wr x 4 wc). Each wave: 64 rows x K=256 of A in
// registers (af[4][8], 128 VGPR); B streams thru 64-code LDS dbuf (2x
// redundancy vs r10's 4x -> LDS reads halved). Positive-biased float-bit
// keys; per-group top-2 retention (covers global approx top-2); fused
// fp64 rescore SKIPPED when approx gap > MARGIN (wave-uniform branch).
__global__ __launch_bounds__(512)
void dist_kernel(const f16* __restrict__ xs, const f16* __restrict__ cs,
                 const float* __restrict__ c2k, const float* __restrict__ x_t,
                 const float* __restrict__ cb, const double* __restrict__ c2d,
                 float* __restrict__ idx_f, int* __restrict__ idx_i) {
    __shared__ f16 Bs[2][64][256];       // 64 KB
    __shared__ u32 red[128][8];          // 4 KB  ([0..3] bins / [4] flag)

    const int tid  = threadIdx.x;
    const int lane = tid & 63;
    const int w    = tid >> 6;           // 0..7
    const int wr   = w >> 2;             // 0..1 row group (64 rows each)
    const int wc   = w & 3;              // 0..3 code column (16 codes/tile)
    const int bid  = blockIdx.x;
    const int q    = bid & 7;
    const int rt   = bid >> 3;
    const int n0   = rt * 128;

    const int c = lane & 15;             // MFMA col / frag row
    const int g = lane >> 4;             // 0..3 k-group

    // ---- A fragments in registers: rows n0 + wr*64 + m*16 + c ----
    f16x8 af[4][8];
    {
        const f16* pa = xs + (size_t)(n0 + wr * 64 + c) * KA + g * 8;
        #pragma unroll
        for (int m = 0; m < 4; ++m)
            #pragma unroll
            for (int kk = 0; kk < 8; ++kk)
                af[m][kk] = *(const f16x8*)(pa + m * 16 * KA + kk * 32);
    }

    // ---- staging: 4 x gll16 per thread per tile (512 thr x 4 x 16B = 32KB)
    const int crow0 = tid >> 5;                    // 0..15
    const int slotl = (tid & 31) ^ (crow0 & 7);    // inverse-swizzled source
    const f16* srcb = cs + (size_t)q * 1024 * KB + (size_t)crow0 * KB
                         + slotl * 8;
    const int dstw = w * 512;                      // wave-uniform dest (f16)

    #define STAGE(buf, t)                                                    \
        do {                                                                 \
            f16* b0 = &Bs[buf][0][0] + dstw;                                 \
            const f16* s_ = srcb + (size_t)(t) * 64 * KB;                    \
            gll16(s_,                 b0);                                   \
            gll16(s_ + 16 * KB,       b0 + 4096);                            \
            gll16(s_ + 32 * KB,       b0 + 8192);                            \
            gll16(s_ + 48 * KB,       b0 + 12288);                           \
        } while (0)

    // per-(thread,row) top-2 keys: rows (m, r)
    u32 k1[4][4], k2[4][4];
    #pragma unroll
    for (int m = 0; m < 4; ++m)
        #pragma unroll
        for (int r = 0; r < 4; ++r) { k1[m][r] = ~0u; k2[m][r] = ~0u; }

    const float* c2q = c2k + q * BINS;
    const int rowoff = (wc * 16 + c) * 256;        // B frag row base (f16)
    const int sw = c & 7;

    STAGE(0, 0);
    __syncthreads();

    #pragma unroll 1
    for (int t = 0; t < NTILE; ++t) {
        const int buf = t & 1;
        if (t < NTILE - 1) STAGE(buf ^ 1, t + 1);

        f32x4 acc[4];
        #pragma unroll
        for (int m = 0; m < 4; ++m) {
            f32x4 z = {0.f, 0.f, 0.f, 0.f};
            acc[m] = z;
        }

        const f16* bb = &Bs[buf][0][0] + rowoff;
        #pragma unroll
        for (int half = 0; half < 2; ++half) {
            f16x8 bg[4];
            #pragma unroll
            for (int k4 = 0; k4 < 4; ++k4) {
                const int kk = half * 4 + k4;
                bg[k4] = *(const f16x8*)(bb + ((kk * 4 + g) ^ sw) * 8);
            }
            #pragma unroll
            for (int k4 = 0; k4 < 4; ++k4)
                #pragma unroll
                for (int m = 0; m < 4; ++m)
                    acc[m] = __builtin_amdgcn_mfma_f32_16x16x32_f16(
                        af[m][half * 4 + k4], bg[k4], acc[m], 0, 0, 0);
        }

        // top-2 insert (6 VALU/score): positive floats -> bits monotone
        const int codeL = t * 64 + wc * 16 + c;
        const float cc = c2q[codeL];
        #pragma unroll
        for (int m = 0; m < 4; ++m)
            #pragma unroll
            for (int r = 0; r < 4; ++r) {
                const float sc = fmaf(-2.f, acc[m][r], cc);
                const u32 key = (__float_as_uint(sc) & 0xFFFFFC00u) | (u32)codeL;
                const u32 hi = k1[m][r] > key ? k1[m][r] : key;
                k1[m][r] = k1[m][r] < key ? k1[m][r] : key;
                k2[m][r] = k2[m][r] < hi ? k2[m][r] : hi;
            }

        __syncthreads();   // drains prefetch (vmcnt0) + publishes buf^1
    }
    #undef STAGE

    // ---- merge: 16 lanes (codes) per row -> wave top2 -> red ----
    #pragma unroll
    for (int m = 0; m < 4; ++m)
        #pragma unroll
        for (int r = 0; r < 4; ++r) {
            u32 a1 = k1[m][r], a2 = k2[m][r];
            #pragma unroll
            for (int mask = 1; mask <= 8; mask <<= 1) {
                const u32 o1 = __shfl_xor(a1, mask, 64);
                const u32 o2 = __shfl_xor(a2, mask, 64);
                const u32 hi = a1 > o1 ? a1 : o1;
                a1 = a1 < o1 ? a1 : o1;
                const u32 lo2 = o2 < a2 ? o2 : a2;
                a2 = hi < lo2 ? hi : lo2;
            }
            if (c == 0) {
                const int rowl = wr * 64 + m * 16 + g * 4 + r;
                red[rowl][wc * 2]     = a1;
                red[rowl][wc * 2 + 1] = a2;
            }
        }
    __syncthreads();

    // ---- per-row top-4 of the 8 wave-candidates + rescore-needed flag ----
    if (tid < 128) {
        u32 s0 = ~0u, s1 = ~0u, s2 = ~0u, s3 = ~0u;
        #pragma unroll
        for (int jj = 0; jj < 8; ++jj) {
            const u32 k = red[tid][jj];
            if (k < s0)      { s3 = s2; s2 = s1; s1 = s0; s0 = k; }
            else if (k < s1) { s3 = s2; s2 = s1; s1 = k; }
            else if (k < s2) { s3 = s2; s2 = k; }
            else if (k < s3) { s3 = k; }
        }
        const float f0 = __uint_as_float(s0 & 0xFFFFFC00u);
        const float f1 = __uint_as_float(s1 & 0xFFFFFC00u);
        red[tid][0] = s0 & 1023u;
        red[tid][1] = s1 & 1023u;
        red[tid][2] = s2 & 1023u;
        red[tid][3] = s3 & 1023u;
        red[tid][4] = (f1 - f0 <= MARGIN) ? 1u : 0u;
    }
    __syncthreads();

    // ---- fused exact rescore (fp64), margin-skipped; wave w: rows w*16.. ----
    {
        const int cand = lane >> 4;      // 0..3
        const int cg   = lane & 15;      // 16-float chunk of C_
        #pragma unroll 1
        for (int i = 0; i < 16; ++i) {
            const int rl = w * 16 + i;
            const int n  = n0 + rl;
            if (!red[rl][4]) {           // wave-uniform: approx winner exact
                if (lane == 0) {
                    const int win = (int)red[rl][0];
                    idx_f[(size_t)n * NQ + q] = (float)win;
                    idx_i[(size_t)n * NQ + q] = win;
                }
                continue;
            }
            const int bin = (int)red[rl][cand];
            const float* xr = x_t + (size_t)n * C_ + cg * 16;
            const float* cr = cb + ((size_t)(q * BINS + bin)) * C_ + cg * 16;
            double d = 0.0;
            #pragma unroll
            for (int u = 0; u < 4; ++u) {
                const float4 xv = *(const float4*)(xr + u * 4);
                const float4 cv = *(const float4*)(cr + u * 4);
                d += (double)xv.x * cv.x + (double)xv.y * cv.y
                   + (double)xv.z * cv.z + (double)xv.w * cv.w;
            }
            #pragma unroll
            for (int off = 8; off; off >>= 1) d += __shfl_down(d, off, 16);
            const double dist = c2d[q * BINS + bin] - 2.0 * d; // valid @ cand*16
            // FULL-WAVE uniform broadcasts (all 64 lanes active here):
            const double d0 = __shfl(dist,  0, 64);
            const double d1 = __shfl(dist, 16, 64);
            const double d2 = __shfl(dist, 32, 64);
            const double d3 = __shfl(dist, 48, 64);
            if (lane == 0) {
                const int b0 = (int)red[rl][0], b1 = (int)red[rl][1];
                const int b2 = (int)red[rl][2], b3 = (int)red[rl][3];
                double best = d0;
                int win = b0;
                if (d1 < best || (d1 == best && b1 < win)) { best = d1; win = b1; }
                if (d2 < best || (d2 == best && b2 < win)) { best = d2; win = b2; }
                if (d3 < best || (d3 == best && b3 < win)) { best = d3; win = b3; }
                idx_f[(size_t)n * NQ + q] = (float)win;
                idx_i[(size_t)n * NQ + q] = win;
            }
        }
    }
}

// ---------------- gather: q_ste output + loss ----------------------------
__global__ __launch_bounds__(256)
void gather_kernel(const float* __restrict__ x, const float* __restrict__ cb,
                   const int* __restrict__ idx_i, float* __restrict__ out,
                   float* __restrict__ loss) {
    __shared__ float ql[C_][17];
    const int blk = blockIdx.x;
    const int b   = blk >> 7;
    const int t0  = (blk & 127) << 4;
    const int tid = threadIdx.x;
    {
        const int c = tid;
        for (int nl = 0; nl < 16; ++nl) {
            const int n = b * T_ + t0 + nl;
            float acc = 0.f;
            #pragma unroll
            for (int qq = 0; qq < NQ; ++qq) {
                const int id = idx_i[(size_t)n * NQ + qq];
                acc += cb[((size_t)qq * BINS + id) * C_ + c];
            }
            ql[c][nl] = acc;
        }
    }
    __syncthreads();
    const int tx = tid & 15, ty = tid >> 4;
    float lsum = 0.f;
    for (int cg = 0; cg < 16; ++cg) {
        const int c = cg * 16 + ty;
        const size_t off = ((size_t)b * C_ + c) * T_ + t0 + tx;
        const float qv = ql[c][tx];
        const float xv = x[off];
        out[off] = qv;
        const float d = qv - xv;
        lsum += d * d;
    }
    #pragma unroll
    for (int off = 32; off; off >>= 1) lsum += __shfl_down(lsum, off, 64);
    if ((tid & 63) == 0)
        atomicAdd(loss, lsum * (2.0f / (float)(B_ * C_ * T_)));
}

extern "C" void kernel_launch(void* const* d_in, const int* in_sizes, int n_in,
                              void* d_out, int out_size, void* d_ws, size_t ws_size,
                              hipStream_t stream) {
    const float* x  = (const float*)d_in[0];
    const float* cb = (const float*)d_in[1];

    float* out   = (float*)d_out;
    float* idx_f = out + (size_t)B_ * C_ * T_;
    float* loss  = idx_f + (size_t)NROWS * NQ;

    char* ws = (char*)d_ws;
    f16*    xs    = (f16*)(ws + XS_OFF);
    f16*    cs    = (f16*)(ws + CS_OFF);
    float*  x_t   = (float*)(ws + XT_OFF);
    double* c2d   = (double*)(ws + C2D_OFF);
    float*  c2k   = (float*)(ws + C2K_OFF);
    int*    idx_i = (int*)(ws + IDXI_OFF);

    hipMemsetAsync(loss, 0, sizeof(float), stream);
    prep_x<<<1024, 256, 0, stream>>>(x, x_t, xs);
    prep_cb_c2<<<2048, 256, 0, stream>>>(cb, cs, c2d, c2k);
    dist_kernel<<<1024, 512, 0, stream>>>(xs, cs, c2k, x_t, cb, c2d,
                                          idx_f, idx_i);
    gather_kernel<<<B_ * (T_ / 16), 256, 0, stream>>>(x, cb, idx_i, out, loss);
}